// Round 8
// baseline (417.494 us; speedup 1.0000x reference)
//
#include <hip/hip_runtime.h>
#include <hip/hip_bf16.h>
#include <stdint.h>
#include <math.h>

// Problem constants (B=1)
#define cH    2048
#define cQ    1024
#define cNH   32
#define cNKV  8
#define cKB   2048

#define INV_BIG   (1.0f/4194304.0f)   // 1/(2048*2048)
#define INV_SMALL (1.0f/1048576.0f)   // 1/(512*2048)

// ---------------------------------------------------------------------------
// Workspace layout (bytes). Total = 46,407,936 (<= proven 48,242,944).
#define WS_SUMS 0           // 8 doubles (5 used)
#define WS_DQ1  256         // 1024 f32
#define WS_DQ2  4352        // 1024 f32
#define WS_XQ   8448        // 1024x2048 bf16 (xq1; reused as xq2 after attention)
#define WS_WALL 4202752     // 5120x2048 bf16 weights; DEAD after fused GEMM ->
                            //   vtKBhi 8MB frag-tiles [h*32+kt], vtKBlo at +8MB,
                            //   vtPhi 1MB frag-tiles [hkv*16+kt] at +16MB, vtPlo +17MB
#define WS_QB   25174272    // 1024x2048 f32 rotated q; reused as wqo after attn
#define WS_KB   33562880    // prompt K planes: KPhi 1MB frag-tiles, KPlo +1MB
#define WS_VB   35660032    // 1024x512 f32 v (source for vtrans)
#define WS_QN   37757184    // 1024x2048 f32 kb_q; reused as CTX (same rows+cols per block)
#define WS_ROPET 46145792   // 1024x32 float2 cos/sin table (262,144 B)

// Fragment-ordered 8KB tile plane: fragment f = kk*4 + nt (kk = inner-dim>>5,
// nt = outer-dim>>4); within fragment, lane = (outer&15) + 16*((inner&31)>>3),
// elem j = inner&7. One fragment = 64 lanes x 16B = 1KB, loads coalesced.

using short8  = __attribute__((ext_vector_type(8))) short;
using floatx4 = __attribute__((ext_vector_type(4))) float;

__device__ __forceinline__ void bsplit(float x, unsigned short& hi, unsigned short& lo) {
  __hip_bfloat16 h = __float2bfloat16(x);          // RN
  float hf = __bfloat162float(h);
  __hip_bfloat16 l = __float2bfloat16(x - hf);     // exact residual, RN again
  hi = *(unsigned short*)&h;
  lo = *(unsigned short*)&l;
}

__device__ __forceinline__ unsigned short tern(float v, float ws) {
  float q = rintf(v * ws);
  q = fminf(fmaxf(q, -1.0f), 1.0f);
  return (unsigned short)(__float_as_uint(q) >> 16);
}

// Async 16B global->LDS (direct-to-shared DMA; dest = wave-uniform base + lane*16).
__device__ __forceinline__ void gload16(const void* g, void* l) {
  __builtin_amdgcn_global_load_lds((const __attribute__((address_space(1))) void*)g,
                                   (__attribute__((address_space(3))) void*)l, 16, 0, 0);
}

// ---------------------------------------------------------------------------
// RoPE cos/sin table: 1024 positions x 32 freqs, fp64 math once.
__global__ void k_ropetab(const int* __restrict__ pos, float2* __restrict__ tab) {
  int i = blockIdx.x * 256 + threadIdx.x;   // 32768
  int t = i >> 5, d = i & 31;
  double p = (double)pos[t];
  double ang = p * pow(10000.0, -(double)d / 32.0);
  tab[i] = make_float2((float)cos(ang), (float)sin(ang));
}

// ---------------------------------------------------------------------------
__global__ void k_abssum5(const float* __restrict__ w0, const float* __restrict__ w1,
                          const float* __restrict__ w2, const float* __restrict__ w3,
                          const float* __restrict__ w4, double* __restrict__ out) {
  __shared__ double red[256];
  const int seg = blockIdx.y;
  const float* w = seg == 0 ? w0 : seg == 1 ? w1 : seg == 2 ? w2 : seg == 3 ? w3 : w4;
  const int n4 = ((seg == 1 || seg == 2) ? 512 * 2048 : 2048 * 2048) / 4;
  double s = 0.0;
  for (int i = blockIdx.x * 256 + threadIdx.x; i < n4; i += gridDim.x * 256) {
    float4 x = *(const float4*)(w + (size_t)i * 4);
    s += (double)fabsf(x.x) + (double)fabsf(x.y) + (double)fabsf(x.z) + (double)fabsf(x.w);
  }
  red[threadIdx.x] = s;
  __syncthreads();
  for (int o = 128; o > 0; o >>= 1) {
    if ((int)threadIdx.x < o) red[threadIdx.x] += red[threadIdx.x + o];
    __syncthreads();
  }
  if (threadIdx.x == 0) atomicAdd(out + seg, red[0]);
}

// Fused ternary quant of Wq/Wk/Wv/Wqn (4 elems/thread; segment bounds are /4).
__global__ void k_wquant4(const float* __restrict__ Wq, const float* __restrict__ Wk,
                          const float* __restrict__ Wv, const float* __restrict__ Wqn,
                          unsigned short* __restrict__ wall, const double* __restrict__ sums) {
  size_t i = ((size_t)blockIdx.x * 256 + threadIdx.x) * 4;   // 0 .. 10485756
  const float* src; size_t off; double s; float inv;
  if (i < 4194304)      { src = Wq;  off = 0;       s = sums[0]; inv = INV_BIG; }
  else if (i < 5242880) { src = Wk;  off = 4194304; s = sums[1]; inv = INV_SMALL; }
  else if (i < 6291456) { src = Wv;  off = 5242880; s = sums[2]; inv = INV_SMALL; }
  else                  { src = Wqn; off = 6291456; s = sums[4]; inv = INV_BIG; }
  float ws = 1.0f / fmaxf((float)s * inv, 1e-5f);
  float4 x = *(const float4*)(src + (i - off));
  ushort4 o;
  o.x = tern(x.x, ws); o.y = tern(x.y, ws); o.z = tern(x.z, ws); o.w = tern(x.w, ws);
  *(ushort4*)(wall + i) = o;
}

// Single-weight ternary quant (Wo), 4 elems/thread.
__global__ void k_wquant(const float* __restrict__ w, unsigned short* __restrict__ wq,
                         const double* __restrict__ sum, float inv_n) {
  size_t i = ((size_t)blockIdx.x * 256 + threadIdx.x) * 4;
  float ws = 1.0f / fmaxf((float)(*sum) * inv_n, 1e-5f);
  float4 x = *(const float4*)(w + i);
  ushort4 o;
  o.x = tern(x.x, ws); o.y = tern(x.y, ws); o.z = tern(x.z, ws); o.w = tern(x.w, ws);
  *(ushort4*)(wq + i) = o;
}

// Per-token int8 absmax activation quant -> bf16 integer values (float4 path).
__global__ void k_aquant(const float* __restrict__ x, unsigned short* __restrict__ xq,
                         float* __restrict__ dq, int K) {
  int t = blockIdx.x;
  const float4* xr = (const float4*)(x + (size_t)t * K);
  const int K4 = K / 4;
  __shared__ float red[256];
  float m = 0.0f;
  for (int i = threadIdx.x; i < K4; i += 256) {
    float4 v = xr[i];
    m = fmaxf(m, fmaxf(fmaxf(fabsf(v.x), fabsf(v.y)), fmaxf(fabsf(v.z), fabsf(v.w))));
  }
  red[threadIdx.x] = m;
  __syncthreads();
  for (int o = 128; o > 0; o >>= 1) {
    if ((int)threadIdx.x < o) red[threadIdx.x] = fmaxf(red[threadIdx.x], red[threadIdx.x + o]);
    __syncthreads();
  }
  float amax = fmaxf(red[0], 1e-5f);
  float as = 127.0f / amax;
  ushort4* xo = (ushort4*)(xq + (size_t)t * K);
  for (int i = threadIdx.x; i < K4; i += 256) {
    float4 v = xr[i];
    ushort4 o;
    float q;
    q = fminf(fmaxf(rintf(v.x * as), -128.0f), 127.0f); o.x = (unsigned short)(__float_as_uint(q) >> 16);
    q = fminf(fmaxf(rintf(v.y * as), -128.0f), 127.0f); o.y = (unsigned short)(__float_as_uint(q) >> 16);
    q = fminf(fmaxf(rintf(v.z * as), -128.0f), 127.0f); o.z = (unsigned short)(__float_as_uint(q) >> 16);
    q = fminf(fmaxf(rintf(v.w * as), -128.0f), 127.0f); o.w = (unsigned short)(__float_as_uint(q) >> 16);
    xo[i] = o;
  }
  if (threadIdx.x == 0) dq[t] = amax / 127.0f;
}

// ---------------------------------------------------------------------------
// bf16-MFMA BitLinear GEMM, 128x128 tiles. Staging via global_load_lds DMA
// (linear LDS dest, XOR-swizzled source cols, swizzled fragment reads) with a
// double-buffered counted-vmcnt pipeline (r7: -20us on the non-attn tail).
// RoPE fused into the epilogue.
__global__ __launch_bounds__(256) void k_gemm_mfma(
    const unsigned short* __restrict__ Aq, const unsigned short* __restrict__ Ball,
    const float* __restrict__ adq, const double* __restrict__ sums,
    const float2* __restrict__ ropetab,
    float* __restrict__ oQ, unsigned short* __restrict__ oKhi,
    unsigned short* __restrict__ oKlo,
    float* __restrict__ oV, float* __restrict__ oQN, int mode) {
  __shared__ __attribute__((aligned(16))) unsigned short As[2][128 * 64];
  __shared__ __attribute__((aligned(16))) unsigned short Bs[2][128 * 64];
  const int t = threadIdx.x;
  const int lane = t & 63;
  const int row16 = lane & 15, q = lane >> 4;
  const int w = t >> 6;
  const int wm = (w >> 1) * 64, wn = (w & 1) * 64;
  const int bx = blockIdx.x;
  const int m0 = blockIdx.y * 128;
  const unsigned short* Bp = Ball + (size_t)bx * 128 * 2048;
  const int swr = row16 & 7;                 // fragment-read XOR key

  floatx4 acc[4][4];
#pragma unroll
  for (int g = 0; g < 4; ++g)
#pragma unroll
    for (int h = 0; h < 4; ++h) acc[g][h] = (floatx4){0.f, 0.f, 0.f, 0.f};

  auto stageAB = [&](int k0s, int b) {
#pragma unroll
    for (int i = 0; i < 4; ++i) {
      int c = t + 256 * i;
      int row = c >> 3, g8 = c & 7;
      int sa = (g8 ^ (row & 7)) * 8;         // source col slot swizzle
      gload16(Aq + (size_t)(m0 + row) * 2048 + k0s + sa, &As[b][w * 512 + i * 2048]);
      gload16(Bp + (size_t)row * 2048 + k0s + sa, &Bs[b][w * 512 + i * 2048]);
    }
  };

  stageAB(0, 0);   // prologue: 8 DMA outstanding
  for (int k0 = 0; k0 < 2048; k0 += 64) {
    const int cur = (k0 >> 6) & 1;
    const int kn = (k0 + 64 < 2048) ? k0 + 64 : k0;   // clamped redundant last
    stageAB(kn, cur ^ 1);                             // +8 -> 16 outstanding
    asm volatile("s_waitcnt vmcnt(8)" ::: "memory");  // wait current tile's 8
    __builtin_amdgcn_s_barrier();
#pragma unroll
    for (int kk = 0; kk < 2; ++kk) {
      short8 af[4], bf[4];
      const int sw = ((kk * 4 + q) ^ swr) << 3;
#pragma unroll
      for (int g = 0; g < 4; ++g)
        af[g] = *(const short8*)&As[cur][(wm + g * 16 + row16) * 64 + sw];
#pragma unroll
      for (int h = 0; h < 4; ++h)
        bf[h] = *(const short8*)&Bs[cur][(wn + h * 16 + row16) * 64 + sw];
#pragma unroll
      for (int g = 0; g < 4; ++g)
#pragma unroll
        for (int h = 0; h < 4; ++h)
          acc[g][h] = __builtin_amdgcn_mfma_f32_16x16x32_bf16(af[g], bf[h], acc[g][h], 0, 0, 0);
    }
    __builtin_amdgcn_s_barrier();   // reads of buf[cur] done before it is re-staged
  }
  asm volatile("s_waitcnt vmcnt(0)" ::: "memory");   // drain redundant last prefetch

  float* outp = nullptr; int Nout = 0, nb0; float wdq;
  if (mode == 1)      { outp = oQ;  Nout = 2048; nb0 = bx * 128;        wdq = fmaxf((float)sums[3] * INV_BIG,   1e-5f); }
  else if (bx < 16)   { outp = oQ;  Nout = 2048; nb0 = bx * 128;        wdq = fmaxf((float)sums[0] * INV_BIG,   1e-5f); }
  else if (bx < 20)   {             Nout = 512;  nb0 = (bx - 16) * 128; wdq = fmaxf((float)sums[1] * INV_SMALL, 1e-5f); }
  else if (bx < 24)   { outp = oV;  Nout = 512;  nb0 = (bx - 20) * 128; wdq = fmaxf((float)sums[2] * INV_SMALL, 1e-5f); }
  else                { outp = oQN; Nout = 2048; nb0 = (bx - 24) * 128; wdq = fmaxf((float)sums[4] * INV_BIG,   1e-5f); }

  if (mode == 0 && bx < 20) {
    // RoPE epilogue. head-relative d = (wn + h*16 + row16) & 63 = h*16 + row16.
#pragma unroll
    for (int g = 0; g < 4; ++g)
#pragma unroll
      for (int r = 0; r < 4; ++r) {
        int m = m0 + wm + g * 16 + q * 4 + r;
        float s = adq[m] * wdq;
        float2 cs0 = ropetab[m * 32 + row16];        // d = row16
        float2 cs1 = ropetab[m * 32 + 16 + row16];   // d = 16 + row16
        float v0 = acc[g][0][r] * s, v1 = acc[g][1][r] * s;
        float v2 = acc[g][2][r] * s, v3 = acc[g][3][r] * s;
        float o0 = v0 * cs0.x - v2 * cs0.y;
        float o2 = v2 * cs0.x + v0 * cs0.y;
        float o1 = v1 * cs1.x - v3 * cs1.y;
        float o3 = v3 * cs1.x + v1 * cs1.y;
        if (bx < 16) {   // Q: fp32
          size_t base = (size_t)m * Nout + nb0 + wn;
          outp[base + row16]      = o0;
          outp[base + 16 + row16] = o1;
          outp[base + 32 + row16] = o2;
          outp[base + 48 + row16] = o3;
        } else {
          // K: RN-bsplit into fragment-ordered hi/lo planes.
          // value o_h: key rr = m&63 (tile kt_ = m>>6), d = h*16 + row16.
          int hkv_ = (nb0 + wn) >> 6;
          int kt_ = m >> 6, rr = m & 63;
          size_t tb = ((size_t)(hkv_ * 16 + kt_)) * 4096;
          int lbase = (rr & 15) + ((row16 >> 3) << 4);
          int ntb = (rr >> 4) * 512 + (row16 & 7);
          unsigned short hi, lo; int ix;
          bsplit(o0, hi, lo); ix = ntb + (lbase     ) * 8;          oKhi[tb + ix] = hi; oKlo[tb + ix] = lo;
          bsplit(o1, hi, lo); ix = ntb + (lbase + 32) * 8;          oKhi[tb + ix] = hi; oKlo[tb + ix] = lo;
          bsplit(o2, hi, lo); ix = ntb + (lbase     ) * 8 + 2048;   oKhi[tb + ix] = hi; oKlo[tb + ix] = lo;
          bsplit(o3, hi, lo); ix = ntb + (lbase + 32) * 8 + 2048;   oKhi[tb + ix] = hi; oKlo[tb + ix] = lo;
        }
      }
  } else {
#pragma unroll
    for (int g = 0; g < 4; ++g)
#pragma unroll
      for (int r = 0; r < 4; ++r) {
        int m = m0 + wm + g * 16 + q * 4 + r;
        float s = adq[m] * wdq;
#pragma unroll
        for (int h = 0; h < 4; ++h)
          outp[(size_t)m * Nout + nb0 + wn + h * 16 + row16] = acc[g][h][r] * s;
      }
  }
}

// ---------------------------------------------------------------------------
// O-projection GEMM, 64x64 tiles: grid 32x16 = 512 blocks (2/CU). Same DMA
// staging + counted-vmcnt double buffer.
__global__ __launch_bounds__(256) void k_gemm64(
    const unsigned short* __restrict__ Aq, const unsigned short* __restrict__ Bq,
    const float* __restrict__ adq, const double* __restrict__ sums,
    float* __restrict__ out) {
  __shared__ __attribute__((aligned(16))) unsigned short As[2][64 * 64];
  __shared__ __attribute__((aligned(16))) unsigned short Bs[2][64 * 64];
  const int t = threadIdx.x;
  const int lane = t & 63;
  const int row16 = lane & 15, q = lane >> 4;
  const int w = t >> 6;
  const int wm = (w >> 1) * 32, wn = (w & 1) * 32;
  const int nb0 = blockIdx.x * 64;
  const int m0 = blockIdx.y * 64;
  const int swr = row16 & 7;

  floatx4 acc[2][2];
#pragma unroll
  for (int g = 0; g < 2; ++g)
#pragma unroll
    for (int h = 0; h < 2; ++h) acc[g][h] = (floatx4){0.f, 0.f, 0.f, 0.f};

  auto stageAB = [&](int k0s, int b) {
#pragma unroll
    for (int i = 0; i < 2; ++i) {
      int c = t + 256 * i;
      int row = c >> 3, g8 = c & 7;
      int sa = (g8 ^ (row & 7)) * 8;
      gload16(Aq + (size_t)(m0 + row) * 2048 + k0s + sa, &As[b][w * 512 + i * 2048]);
      gload16(Bq + (size_t)(nb0 + row) * 2048 + k0s + sa, &Bs[b][w * 512 + i * 2048]);
    }
  };

  stageAB(0, 0);
  for (int k0 = 0; k0 < 2048; k0 += 64) {
    const int cur = (k0 >> 6) & 1;
    const int kn = (k0 + 64 < 2048) ? k0 + 64 : k0;
    stageAB(kn, cur ^ 1);
    asm volatile("s_waitcnt vmcnt(4)" ::: "memory");
    __builtin_amdgcn_s_barrier();
#pragma unroll
    for (int kk = 0; kk < 2; ++kk) {
      short8 af[2], bf[2];
      const int sw = ((kk * 4 + q) ^ swr) << 3;
#pragma unroll
      for (int g = 0; g < 2; ++g)
        af[g] = *(const short8*)&As[cur][(wm + g * 16 + row16) * 64 + sw];
#pragma unroll
      for (int h = 0; h < 2; ++h)
        bf[h] = *(const short8*)&Bs[cur][(wn + h * 16 + row16) * 64 + sw];
#pragma unroll
      for (int g = 0; g < 2; ++g)
#pragma unroll
        for (int h = 0; h < 2; ++h)
          acc[g][h] = __builtin_amdgcn_mfma_f32_16x16x32_bf16(af[g], bf[h], acc[g][h], 0, 0, 0);
    }
    __builtin_amdgcn_s_barrier();
  }
  asm volatile("s_waitcnt vmcnt(0)" ::: "memory");

  float wdq = fmaxf((float)sums[3] * INV_BIG, 1e-5f);
#pragma unroll
  for (int g = 0; g < 2; ++g)
#pragma unroll
    for (int r = 0; r < 4; ++r) {
      int m = m0 + wm + g * 16 + q * 4 + r;
      float s = adq[m] * wdq;
#pragma unroll
      for (int h = 0; h < 2; ++h)
        out[(size_t)m * 2048 + nb0 + wn + h * 16 + row16] = acc[g][h][r] * s;
    }
}

// ---------------------------------------------------------------------------
// Merged prep. All outputs are 8KB fragment-ordered ushort tile planes (see
// header comment) so attention loads fragments global->VGPR fully coalesced.
//   blocks [0,1024):    vtKB  (transpose kbv -> V^T, RN-bsplit hi/lo planes)
//   blocks [1024,1152): vtP   (transpose Vb  -> V^T, RN-bsplit hi/lo planes)
//   blocks >= 1152:     kbk   in-place tile split [key][d] -> [hi 8KB | lo 8KB]
__global__ __launch_bounds__(256) void k_prep(
    const float* __restrict__ kbv, const float* __restrict__ Vb,
    unsigned short* __restrict__ vtKBhi, unsigned short* __restrict__ vtPhi,
    float* __restrict__ kbk) {
  const int b = blockIdx.x;
  const int t = threadIdx.x;
  if (b >= 1152) {
    float* tile = kbk + (size_t)(b - 1152) * 4096;   // 64x64 f32 [key][d], contiguous
    float v[2][8];
#pragma unroll
    for (int u = 0; u < 2; ++u) {
      int task = t + 256 * u;            // 512 tasks: key r = task>>3, d-slot s = task&7
      int r = task >> 3, s = task & 7;
      *(float4*)&v[u][0] = *(const float4*)(tile + r * 64 + s * 8);
      *(float4*)&v[u][4] = *(const float4*)(tile + r * 64 + s * 8 + 4);
    }
    __syncthreads();                     // all reads before any in-place write
    unsigned short* up = (unsigned short*)tile;
#pragma unroll
    for (int u = 0; u < 2; ++u) {
      int task = t + 256 * u;
      int r = task >> 3, s = task & 7;   // element (key=r, d=s*8+j)
      union { unsigned short u16[8]; uint4 q; } hi, lo;
#pragma unroll
      for (int j = 0; j < 8; ++j) bsplit(v[u][j], hi.u16[j], lo.u16[j]);
      // K-frag: frag = (d>>5)*4 + (key>>4); lane = (key&15) + 16*((d&31)>>3); j = d&7
      size_t off = (size_t)(((s >> 2) * 4 + (r >> 4)) * 512 + ((r & 15) + ((s & 3) << 4)) * 8);
      *(uint4*)(up + off)        = hi.q;
      *(uint4*)(up + 4096 + off) = lo.q;
    }
    return;
  }
  __shared__ float Lf[64 * 65];
  const float* src; unsigned short *dhi, *dlo; int srcStride;
  if (b < 1024) {
    int h = b >> 5, kt = b & 31;
    src = kbv + ((size_t)h * cKB + kt * 64) * 64; srcStride = 64;
    dhi = vtKBhi + (size_t)b * 4096; dlo = dhi + 4194304;
  } else {
    int bb = b - 1024;
    int hkv = bb >> 4, kt = bb & 15;
    src = Vb + (size_t)(kt * 64) * 512 + hkv * 64; srcStride = 512;
    dhi = vtPhi + (size_t)bb * 4096; dlo = dhi + 524288;
  }
#pragma unroll
  for (int i = 0; i < 4; ++i) {
    int c = t + 256 * i;
    int row = c >> 4, c4 = (c & 15) * 4;       // row = key, col = d
    float4 x = *(const float4*)(src + (size_t)row * srcStride + c4);
    Lf[row * 65 + c4 + 0] = x.x;
    Lf[row * 65 + c4 + 1] = x.y;
    Lf[row * 65 + c4 + 2] = x.z;
    Lf[row * 65 + c4 + 3] = x.w;
  }
  __syncthreads();
#pragma unroll
  for (int u = 0; u < 2; ++u) {
    int task = t + 256 * u;                    // d = task>>3, key slot s = task&7
    int d = task >> 3, s = task & 7;           // element (d, key=s*8+j)
    union { unsigned short u16[8]; uint4 q; } hi, lo;
#pragma unroll
    for (int j = 0; j < 8; ++j) bsplit(Lf[(s * 8 + j) * 65 + d], hi.u16[j], lo.u16[j]);
    // V^T-frag: frag = (key>>5)*4 + (d>>4); lane = (d&15) + 16*((key&31)>>3); j = key&7
    size_t off = (size_t)(((s >> 2) * 4 + (d >> 4)) * 512 + ((d & 15) + ((s & 3) << 4)) * 8);
    *(uint4*)(dhi + off) = hi.q;
    *(uint4*)(dlo + off) = lo.q;
  }
}

// ---------------------------------------------------------------------------
// Split-bf16 MFMA flash attention, register-direct K/V with 32 q-rows/wave:
// blocks of 128 threads (2 waves), grid 32x16 = 512 blocks (2/CU, 4 waves/CU,
// 1 wave/SIMD). Each wave still loads the full 32KB K+V tile, but amortizes
// it over 2x the output rows -> L1-port traffic per CU-tile-slot halves
// (256KB -> 128KB; r4-r7 measured ~4235 cyc/tile-slot == the 256KB/64B L1
// floor). VGPR ~350 is fine at 1 wave/SIMD (budget 512).
__global__ __launch_bounds__(128, 1) void k_attn_mfma(
    const float* __restrict__ Qr, float* qnctx,
    const unsigned short* __restrict__ KPhi,    // prompt K planes, lo at +524288
    const unsigned short* __restrict__ kbkS,    // KB K tiles [h*32+kt][hi 4096 | lo 4096]
    const unsigned short* __restrict__ vtKBhi,  // KB V^T planes, lo at +4194304
    const unsigned short* __restrict__ vtPhi) { // prompt V^T planes, lo at +524288
  __shared__ __attribute__((aligned(16))) unsigned int Pbuf[2][32 * 68];   // per-wave

  const int t = threadIdx.x;
  const int lane = t & 63;
  const int col = lane & 15;
  const int quad = lane >> 4;
  const int w = t >> 6;                        // 0..1
  const int h = blockIdx.x;
  const int q0 = blockIdx.y * 64;
  const int hkv = h >> 2;
  const float kbbias = 0.69314718055994531f;   // log(4096)-log(2048)
  unsigned int* Pw = &Pbuf[w][0];
  const int fl = lane * 8;                     // fragment lane offset (ushorts)

  // Q fragments: [g][kk], rows q0 + w*32 + g*16 + col.
  short8 qAh[2][2], qAl[2][2];   // kb_q (not rotated)
  short8 qBh[2][2], qBl[2][2];   // rotated prompt q
#pragma unroll
  for (int g = 0; g < 2; ++g)
#pragma unroll
    for (int kk = 0; kk < 2; ++kk) {
      const size_t off = (size_t)(q0 + w * 32 + g * 16 + col) * 2048 + h * 64 + kk * 32 + quad * 8;
      float4 a = *(const float4*)(qnctx + off);
      float4 b = *(const float4*)(qnctx + off + 4);
      float xs[8] = {a.x, a.y, a.z, a.w, b.x, b.y, b.z, b.w};
#pragma unroll
      for (int j = 0; j < 8; ++j) {
        unsigned short hi, lo;
        bsplit(xs[j] * 0.125f, hi, lo);   // fold 1/sqrt(64), exact
        qAh[g][kk][j] = (short)hi; qAl[g][kk][j] = (short)lo;
      }
      float4 c = *(const float4*)(Qr + off);
      float4 d = *(const float4*)(Qr + off + 4);
      float ys[8] = {c.x, c.y, c.z, c.w, d.x, d.y, d.z, d.w};
#pragma unroll
      for (int j = 0; j < 8; ++j) {
        unsigned short hi, lo;
        bsplit(ys[j] * 0.125f, hi, lo);
        qBh[g][kk][j] = (short)hi; qBl[g][kk][j] = (short)lo;
      }
    }

  floatx4 acco[2][4];
  float m_[2][4], l_[2][4];
#pragma unroll
  for (int g = 0; g < 2; ++g)
#pragma unroll
    for (int nt = 0; nt < 4; ++nt) acco[g][nt] = (floatx4){0.f, 0.f, 0.f, 0.f};
#pragma unroll
  for (int g = 0; g < 2; ++g)
#pragma unroll
    for (int r = 0; r < 4; ++r) { m_[g][r] = -3.0e38f; l_[g][r] = 0.f; }

  const int ntiles = 32 + (q0 >> 6) + 1;

  short8 kh[2][4], kl[2][4];   // K fragments (hi/lo), current tile
  short8 vh[2][4], vl[2][4];   // V^T fragments (hi/lo), current tile

  auto loadK = [&](int kt2) {
    const unsigned short *ph, *pl;
    if (kt2 < 32) { const size_t tk = (size_t)(h * 32 + kt2);
                    ph = kbkS + tk * 8192; pl = ph + 4096; }
    else          { const size_t tk = (size_t)(hkv * 16 + (kt2 - 32));
                    ph = KPhi + tk * 4096; pl = ph + 524288; }
#pragma unroll
    for (int kk = 0; kk < 2; ++kk)
#pragma unroll
      for (int nt = 0; nt < 4; ++nt) {
        kh[kk][nt] = *(const short8*)(ph + (kk * 4 + nt) * 512 + fl);
        kl[kk][nt] = *(const short8*)(pl + (kk * 4 + nt) * 512 + fl);
      }
  };
  auto loadV = [&](int kt2) {
    const unsigned short *ph, *pl;
    if (kt2 < 32) { const size_t tk = (size_t)(h * 32 + kt2);
                    ph = vtKBhi + tk * 4096; pl = ph + 4194304; }
    else          { const size_t tk = (size_t)(hkv * 16 + (kt2 - 32));
                    ph = vtPhi + tk * 4096; pl = ph + 524288; }
#pragma unroll
    for (int kk = 0; kk < 2; ++kk)
#pragma unroll
      for (int nt = 0; nt < 4; ++nt) {
        vh[kk][nt] = *(const short8*)(ph + (kk * 4 + nt) * 512 + fl);
        vl[kk][nt] = *(const short8*)(pl + (kk * 4 + nt) * 512 + fl);
      }
  };

  loadK(0);   // prologue

  for (int kt = 0; kt < ntiles; ++kt) {
    const bool isKB = kt < 32;
    loadV(kt);                          // in flight during QK+softmax
    __builtin_amdgcn_s_barrier();       // convergence only (no shared staging)

    floatx4 accs[2][4];
#pragma unroll
    for (int g = 0; g < 2; ++g)
#pragma unroll
      for (int nt = 0; nt < 4; ++nt) accs[g][nt] = (floatx4){0.f, 0.f, 0.f, 0.f};
    if (isKB) {
#pragma unroll
      for (int g = 0; g < 2; ++g)
#pragma unroll
        for (int kk = 0; kk < 2; ++kk)
#pragma unroll
          for (int nt = 0; nt < 4; ++nt) {
            accs[g][nt] = __builtin_amdgcn_mfma_f32_16x16x32_bf16(qAh[g][kk], kh[kk][nt], accs[g][nt], 0, 0, 0);
            accs[g][nt] = __builtin_amdgcn_mfma_f32_16x16x32_bf16(qAl[g][kk], kh[kk][nt], accs[g][nt], 0, 0, 0);
            accs[g][nt] = __builtin_amdgcn_mfma_f32_16x16x32_bf16(qAh[g][kk], kl[kk][nt], accs[g][nt], 0, 0, 0);
          }
    } else {
#pragma unroll
      for (int g = 0; g < 2; ++g)
#pragma unroll
        for (int kk = 0; kk < 2; ++kk)
#pragma unroll
          for (int nt = 0; nt < 4; ++nt) {
            accs[g][nt] = __builtin_amdgcn_mfma_f32_16x16x32_bf16(qBh[g][kk], kh[kk][nt], accs[g][nt], 0, 0, 0);
            accs[g][nt] = __builtin_amdgcn_mfma_f32_16x16x32_bf16(qBl[g][kk], kh[kk][nt], accs[g][nt], 0, 0, 0);
            accs[g][nt] = __builtin_amdgcn_mfma_f32_16x16x32_bf16(qBh[g][kk], kl[kk][nt], accs[g][nt], 0, 0, 0);
          }
    }

    // Bias/mask: KB tiles = uniform bias; prompt non-diagonal = none; only the
    // final (diagonal) tile needs the causal mask.
    float sv[2][4][4];
    if (isKB) {
#pragma unroll
      for (int g = 0; g < 2; ++g)
#pragma unroll
        for (int nt = 0; nt < 4; ++nt)
#pragma unroll
          for (int r = 0; r < 4; ++r) sv[g][nt][r] = accs[g][nt][r] + kbbias;
    } else if (kt < ntiles - 1) {
#pragma unroll
      for (int g = 0; g < 2; ++g)
#pragma unroll
        for (int nt = 0; nt < 4; ++nt)
#pragma unroll
          for (int r = 0; r < 4; ++r) sv[g][nt][r] = accs[g][nt][r];
    } else {
#pragma unroll
      for (int g = 0; g < 2; ++g)
#pragma unroll
        for (int nt = 0; nt < 4; ++nt) {
          int kl_ = nt * 16 + col;
#pragma unroll
          for (int r = 0; r < 4; ++r) {
            int ql_ = w * 32 + g * 16 + quad * 4 + r;
            sv[g][nt][r] = accs[g][nt][r] + ((kl_ <= ql_) ? 0.0f : -1e9f);
          }
        }
    }
#pragma unroll
    for (int g = 0; g < 2; ++g)
#pragma unroll
      for (int r = 0; r < 4; ++r) {
        float rmax = fmaxf(fmaxf(sv[g][0][r], sv[g][1][r]), fmaxf(sv[g][2][r], sv[g][3][r]));
#pragma unroll
        for (int off = 8; off; off >>= 1) rmax = fmaxf(rmax, __shfl_xor(rmax, off));
        float mnew = fmaxf(m_[g][r], rmax);
        float alpha = __expf(m_[g][r] - mnew);
        float psum = 0.f;
#pragma unroll
        for (int nt = 0; nt < 4; ++nt) {
          float p = __expf(sv[g][nt][r] - mnew);
          sv[g][nt][r] = p;
          psum += p;
        }
#pragma unroll
        for (int off = 8; off; off >>= 1) psum += __shfl_xor(psum, off);
        l_[g][r] = l_[g][r] * alpha + psum;
        m_[g][r] = mnew;
#pragma unroll
        for (int nt = 0; nt < 4; ++nt) acco[g][nt][r] *= alpha;
      }

    // Prefetch next tile's K (WAR on kh/kl keeps these after the QK MFMAs;
    // in flight during P-pack + PV). Clamped redundant load on last tile.
    loadK(kt + 1 < ntiles ? kt + 1 : kt);

    // P truncation split -> packed hi|lo<<16 (err <= 2^-16 * p; p in [0,1]).
#pragma unroll
    for (int g = 0; g < 2; ++g)
#pragma unroll
      for (int nt = 0; nt < 4; ++nt)
#pragma unroll
        for (int r = 0; r < 4; ++r) {
          unsigned xb = __float_as_uint(sv[g][nt][r]);
          float hf = __uint_as_float(xb & 0xffff0000u);
          unsigned db = __float_as_uint(sv[g][nt][r] - hf);
          Pw[(g * 16 + quad * 4 + r) * 68 + nt * 16 + col] = (xb >> 16) | (db & 0xffff0000u);
        }

#pragma unroll
    for (int kk = 0; kk < 2; ++kk)
#pragma unroll
      for (int g = 0; g < 2; ++g) {
        uint4 pa = *(const uint4*)&Pw[(g * 16 + col) * 68 + kk * 32 + quad * 8];
        uint4 pb = *(const uint4*)&Pw[(g * 16 + col) * 68 + kk * 32 + quad * 8 + 4];
        union { unsigned int u[4]; short8 s; } uh, ul;
        uh.u[0] = (pa.x & 0xffffu) | (pa.y << 16);
        uh.u[1] = (pa.z & 0xffffu) | (pa.w << 16);
        uh.u[2] = (pb.x & 0xffffu) | (pb.y << 16);
        uh.u[3] = (pb.z & 0xffffu) | (pb.w << 16);
        ul.u[0] = (pa.x >> 16) | (pa.y & 0xffff0000u);
        ul.u[1] = (pa.z >> 16) | (pa.w & 0xffff0000u);
        ul.u[2] = (pb.x >> 16) | (pb.y & 0xffff0000u);
        ul.u[3] = (pb.z >> 16) | (pb.w & 0xffff0000u);
        short8 ph8 = uh.s, pl8 = ul.s;
#pragma unroll
        for (int nt = 0; nt < 4; ++nt) {
          acco[g][nt] = __builtin_amdgcn_mfma_f32_16x16x32_bf16(ph8, vh[kk][nt], acco[g][nt], 0, 0, 0);
          acco[g][nt] = __builtin_amdgcn_mfma_f32_16x16x32_bf16(pl8, vh[kk][nt], acco[g][nt], 0, 0, 0);
          acco[g][nt] = __builtin_amdgcn_mfma_f32_16x16x32_bf16(ph8, vl[kk][nt], acco[g][nt], 0, 0, 0);
        }
      }
  }

#pragma unroll
  for (int g = 0; g < 2; ++g)
#pragma unroll
    for (int r = 0; r < 4; ++r) {
      float linv = 1.0f / l_[g][r];
#pragma unroll
      for (int nt = 0; nt < 4; ++nt)
        qnctx[(size_t)(q0 + w * 32 + g * 16 + quad * 4 + r) * 2048 + h * 64 + nt * 16 + col] =
            acco[g][nt][r] * linv;
    }
}

// ---------------------------------------------------------------------------
extern "C" void kernel_launch(void* const* d_in, const int* in_sizes, int n_in,
                              void* d_out, int out_size, void* d_ws, size_t ws_size,
                              hipStream_t stream) {
  (void)in_sizes; (void)n_in; (void)out_size; (void)ws_size;
  const float* hidden = (const float*)d_in[0];
  float* kbk = (float*)d_in[2];              // tile-split in place (restored each launch)
  const float* kbv = (const float*)d_in[3];
  const float* Wq  = (const float*)d_in[4];
  const float* Wk  = (const float*)d_in[5];
  const float* Wv  = (const float*)d_in[6];
  const float* Wo  = (const float*)d_in[7];
  const float* Wqn = (const float*)d_in[8];
  const int*   pos = (const int*)d_in[9];

  char* ws = (char*)d_ws;
  double* sums = (double*)(ws + WS_SUMS);
  float* dq1 = (float*)(ws + WS_DQ1);
  float* dq2 = (float*)(ws + WS_DQ2);
  unsigned short* xq   = (unsigned short*)(ws + WS_XQ);
  unsigned short* wall = (unsigned short*)(ws + WS_WALL);
  unsigned short* vtKBhi = (unsigned short*)(ws + WS_WALL);              // after GEMM
  unsigned short* vtPhi  = (unsigned short*)(ws + WS_WALL + 16777216);   // after GEMM
  unsigned short* wqo  = (unsigned short*)(ws + WS_QB);                  // after attn
  float* Qb  = (float*)(ws + WS_QB);
  unsigned short* KPhi = (unsigned short*)(ws + WS_KB);                  // prompt K hi
  unsigned short* KPlo = KPhi + 524288;                                  // prompt K lo
  float* Vb  = (float*)(ws + WS_VB);
  float* QNC = (float*)(ws + WS_QN);   // kb_q, then CTX
  float2* ropetab = (float2*)(ws + WS_ROPET);

  hipMemsetAsync(sums, 0, 64, stream);

  k_ropetab<<<128, 256, 0, stream>>>(pos, ropetab);
  k_abssum5<<<dim3(128, 5), 256, 0, stream>>>(Wq, Wk, Wv, Wo, Wqn, sums);
  k_wquant4<<<10240, 256, 0, stream>>>(Wq, Wk, Wv, Wqn, wall, sums);
  k_aquant<<<cQ, 256, 0, stream>>>(hidden, xq, dq1, cH);

  // Fused Q/K/V/QN GEMM with RoPE epilogue: 128x128 tiles, grid 40x8
  k_gemm_mfma<<<dim3(40, 8), 256, 0, stream>>>(xq, wall, dq1, sums, ropetab,
                                               Qb, KPhi, KPlo, Vb, QNC, 0);

  // V transposes (1152 blocks) + kbk in-place tile split (1024 blocks)
  k_prep<<<1152 + 1024, 256, 0, stream>>>(kbv, Vb, vtKBhi, vtPhi, kbk);

  // 2 waves x 32 q-rows per block (128 threads), grid 512 = 2 blocks/CU
  k_attn_mfma<<<dim3(cNH, cQ / 64), 128, 0, stream>>>(
      Qb, QNC, KPhi, (const unsigned short*)kbk, vtKBhi, vtPhi);

  k_wquant<<<4096, 256, 0, stream>>>(Wo, wqo, sums + 3, INV_BIG);
  k_aquant<<<cQ, 256, 0, stream>>>(QNC, xq, dq2, cH);

  // O projection: 64x64 tiles, grid 32x16 = 512 blocks (2/CU)
  k_gemm64<<<dim3(32, 16), 256, 0, stream>>>(xq, wqo, dq2, sums, (float*)d_out);
}

// Round 9
// 390.956 us; speedup vs baseline: 1.0679x; 1.0679x over previous
//
#include <hip/hip_runtime.h>
#include <hip/hip_bf16.h>
#include <stdint.h>
#include <math.h>

// Problem constants (B=1)
#define cH    2048
#define cQ    1024
#define cNH   32
#define cNKV  8
#define cKB   2048

#define INV_BIG   (1.0f/4194304.0f)   // 1/(2048*2048)
#define INV_SMALL (1.0f/1048576.0f)   // 1/(512*2048)

// ---------------------------------------------------------------------------
// Workspace layout (bytes). Total = 46,407,936 (<= proven 48,242,944).
#define WS_SUMS 0           // 8 doubles (5 used)
#define WS_DQ1  256         // 1024 f32
#define WS_DQ2  4352        // 1024 f32
#define WS_XQ   8448        // 1024x2048 bf16 (xq1; reused as xq2 after attention)
#define WS_WALL 4202752     // 5120x2048 bf16 weights; DEAD after fused GEMM ->
                            //   vtKBhi 8MB frag-tiles [h*32+kt], vtKBlo at +8MB,
                            //   vtPhi 1MB frag-tiles [hkv*16+kt] at +16MB, vtPlo +17MB
#define WS_QB   25174272    // 1024x2048 f32 rotated q; reused as wqo after attn
#define WS_KB   33562880    // prompt K planes: KPhi 1MB frag-tiles, KPlo +1MB
#define WS_VB   35660032    // 1024x512 f32 v (source for vtrans)
#define WS_QN   37757184    // 1024x2048 f32 kb_q; reused as CTX (same rows+cols per block)
#define WS_ROPET 46145792   // 1024x32 float2 cos/sin table (262,144 B)

// Fragment-ordered 8KB tile plane: fragment f = kk*4 + nt (kk = inner-dim>>5,
// nt = outer-dim>>4); within fragment, lane = (outer&15) + 16*((inner&31)>>3),
// elem j = inner&7. One fragment = 64 lanes x 16B = 1KB, loads coalesced.

using short8  = __attribute__((ext_vector_type(8))) short;
using floatx4 = __attribute__((ext_vector_type(4))) float;

__device__ __forceinline__ void bsplit(float x, unsigned short& hi, unsigned short& lo) {
  __hip_bfloat16 h = __float2bfloat16(x);          // RN
  float hf = __bfloat162float(h);
  __hip_bfloat16 l = __float2bfloat16(x - hf);     // exact residual, RN again
  hi = *(unsigned short*)&h;
  lo = *(unsigned short*)&l;
}

__device__ __forceinline__ unsigned short tern(float v, float ws) {
  float q = rintf(v * ws);
  q = fminf(fmaxf(q, -1.0f), 1.0f);
  return (unsigned short)(__float_as_uint(q) >> 16);
}

// Async 16B global->LDS (direct-to-shared DMA; dest = wave-uniform base + lane*16).
__device__ __forceinline__ void gload16(const void* g, void* l) {
  __builtin_amdgcn_global_load_lds((const __attribute__((address_space(1))) void*)g,
                                   (__attribute__((address_space(3))) void*)l, 16, 0, 0);
}

// ---------------------------------------------------------------------------
// RoPE cos/sin table: 1024 positions x 32 freqs, fp64 math once.
__global__ void k_ropetab(const int* __restrict__ pos, float2* __restrict__ tab) {
  int i = blockIdx.x * 256 + threadIdx.x;   // 32768
  int t = i >> 5, d = i & 31;
  double p = (double)pos[t];
  double ang = p * pow(10000.0, -(double)d / 32.0);
  tab[i] = make_float2((float)cos(ang), (float)sin(ang));
}

// ---------------------------------------------------------------------------
__global__ void k_abssum5(const float* __restrict__ w0, const float* __restrict__ w1,
                          const float* __restrict__ w2, const float* __restrict__ w3,
                          const float* __restrict__ w4, double* __restrict__ out) {
  __shared__ double red[256];
  const int seg = blockIdx.y;
  const float* w = seg == 0 ? w0 : seg == 1 ? w1 : seg == 2 ? w2 : seg == 3 ? w3 : w4;
  const int n4 = ((seg == 1 || seg == 2) ? 512 * 2048 : 2048 * 2048) / 4;
  double s = 0.0;
  for (int i = blockIdx.x * 256 + threadIdx.x; i < n4; i += gridDim.x * 256) {
    float4 x = *(const float4*)(w + (size_t)i * 4);
    s += (double)fabsf(x.x) + (double)fabsf(x.y) + (double)fabsf(x.z) + (double)fabsf(x.w);
  }
  red[threadIdx.x] = s;
  __syncthreads();
  for (int o = 128; o > 0; o >>= 1) {
    if ((int)threadIdx.x < o) red[threadIdx.x] += red[threadIdx.x + o];
    __syncthreads();
  }
  if (threadIdx.x == 0) atomicAdd(out + seg, red[0]);
}

// Fused ternary quant of Wq/Wk/Wv/Wqn (4 elems/thread; segment bounds are /4).
__global__ void k_wquant4(const float* __restrict__ Wq, const float* __restrict__ Wk,
                          const float* __restrict__ Wv, const float* __restrict__ Wqn,
                          unsigned short* __restrict__ wall, const double* __restrict__ sums) {
  size_t i = ((size_t)blockIdx.x * 256 + threadIdx.x) * 4;   // 0 .. 10485756
  const float* src; size_t off; double s; float inv;
  if (i < 4194304)      { src = Wq;  off = 0;       s = sums[0]; inv = INV_BIG; }
  else if (i < 5242880) { src = Wk;  off = 4194304; s = sums[1]; inv = INV_SMALL; }
  else if (i < 6291456) { src = Wv;  off = 5242880; s = sums[2]; inv = INV_SMALL; }
  else                  { src = Wqn; off = 6291456; s = sums[4]; inv = INV_BIG; }
  float ws = 1.0f / fmaxf((float)s * inv, 1e-5f);
  float4 x = *(const float4*)(src + (i - off));
  ushort4 o;
  o.x = tern(x.x, ws); o.y = tern(x.y, ws); o.z = tern(x.z, ws); o.w = tern(x.w, ws);
  *(ushort4*)(wall + i) = o;
}

// Single-weight ternary quant (Wo), 4 elems/thread.
__global__ void k_wquant(const float* __restrict__ w, unsigned short* __restrict__ wq,
                         const double* __restrict__ sum, float inv_n) {
  size_t i = ((size_t)blockIdx.x * 256 + threadIdx.x) * 4;
  float ws = 1.0f / fmaxf((float)(*sum) * inv_n, 1e-5f);
  float4 x = *(const float4*)(w + i);
  ushort4 o;
  o.x = tern(x.x, ws); o.y = tern(x.y, ws); o.z = tern(x.z, ws); o.w = tern(x.w, ws);
  *(ushort4*)(wq + i) = o;
}

// Per-token int8 absmax activation quant -> bf16 integer values (float4 path).
__global__ void k_aquant(const float* __restrict__ x, unsigned short* __restrict__ xq,
                         float* __restrict__ dq, int K) {
  int t = blockIdx.x;
  const float4* xr = (const float4*)(x + (size_t)t * K);
  const int K4 = K / 4;
  __shared__ float red[256];
  float m = 0.0f;
  for (int i = threadIdx.x; i < K4; i += 256) {
    float4 v = xr[i];
    m = fmaxf(m, fmaxf(fmaxf(fabsf(v.x), fabsf(v.y)), fmaxf(fabsf(v.z), fabsf(v.w))));
  }
  red[threadIdx.x] = m;
  __syncthreads();
  for (int o = 128; o > 0; o >>= 1) {
    if ((int)threadIdx.x < o) red[threadIdx.x] = fmaxf(red[threadIdx.x], red[threadIdx.x + o]);
    __syncthreads();
  }
  float amax = fmaxf(red[0], 1e-5f);
  float as = 127.0f / amax;
  ushort4* xo = (ushort4*)(xq + (size_t)t * K);
  for (int i = threadIdx.x; i < K4; i += 256) {
    float4 v = xr[i];
    ushort4 o;
    float q;
    q = fminf(fmaxf(rintf(v.x * as), -128.0f), 127.0f); o.x = (unsigned short)(__float_as_uint(q) >> 16);
    q = fminf(fmaxf(rintf(v.y * as), -128.0f), 127.0f); o.y = (unsigned short)(__float_as_uint(q) >> 16);
    q = fminf(fmaxf(rintf(v.z * as), -128.0f), 127.0f); o.z = (unsigned short)(__float_as_uint(q) >> 16);
    q = fminf(fmaxf(rintf(v.w * as), -128.0f), 127.0f); o.w = (unsigned short)(__float_as_uint(q) >> 16);
    xo[i] = o;
  }
  if (threadIdx.x == 0) dq[t] = amax / 127.0f;
}

// ---------------------------------------------------------------------------
// bf16-MFMA BitLinear GEMM, 128x128 tiles. Staging via global_load_lds DMA
// (linear LDS dest, XOR-swizzled source cols, swizzled fragment reads) with a
// double-buffered counted-vmcnt pipeline (r7: -20us on the non-attn tail).
// RoPE fused into the epilogue.
__global__ __launch_bounds__(256) void k_gemm_mfma(
    const unsigned short* __restrict__ Aq, const unsigned short* __restrict__ Ball,
    const float* __restrict__ adq, const double* __restrict__ sums,
    const float2* __restrict__ ropetab,
    float* __restrict__ oQ, unsigned short* __restrict__ oKhi,
    unsigned short* __restrict__ oKlo,
    float* __restrict__ oV, float* __restrict__ oQN, int mode) {
  __shared__ __attribute__((aligned(16))) unsigned short As[2][128 * 64];
  __shared__ __attribute__((aligned(16))) unsigned short Bs[2][128 * 64];
  const int t = threadIdx.x;
  const int lane = t & 63;
  const int row16 = lane & 15, q = lane >> 4;
  const int w = t >> 6;
  const int wm = (w >> 1) * 64, wn = (w & 1) * 64;
  const int bx = blockIdx.x;
  const int m0 = blockIdx.y * 128;
  const unsigned short* Bp = Ball + (size_t)bx * 128 * 2048;
  const int swr = row16 & 7;                 // fragment-read XOR key

  floatx4 acc[4][4];
#pragma unroll
  for (int g = 0; g < 4; ++g)
#pragma unroll
    for (int h = 0; h < 4; ++h) acc[g][h] = (floatx4){0.f, 0.f, 0.f, 0.f};

  auto stageAB = [&](int k0s, int b) {
#pragma unroll
    for (int i = 0; i < 4; ++i) {
      int c = t + 256 * i;
      int row = c >> 3, g8 = c & 7;
      int sa = (g8 ^ (row & 7)) * 8;         // source col slot swizzle
      gload16(Aq + (size_t)(m0 + row) * 2048 + k0s + sa, &As[b][w * 512 + i * 2048]);
      gload16(Bp + (size_t)row * 2048 + k0s + sa, &Bs[b][w * 512 + i * 2048]);
    }
  };

  stageAB(0, 0);   // prologue: 8 DMA outstanding
  for (int k0 = 0; k0 < 2048; k0 += 64) {
    const int cur = (k0 >> 6) & 1;
    const int kn = (k0 + 64 < 2048) ? k0 + 64 : k0;   // clamped redundant last
    stageAB(kn, cur ^ 1);                             // +8 -> 16 outstanding
    asm volatile("s_waitcnt vmcnt(8)" ::: "memory");  // wait current tile's 8
    __builtin_amdgcn_s_barrier();
#pragma unroll
    for (int kk = 0; kk < 2; ++kk) {
      short8 af[4], bf[4];
      const int sw = ((kk * 4 + q) ^ swr) << 3;
#pragma unroll
      for (int g = 0; g < 4; ++g)
        af[g] = *(const short8*)&As[cur][(wm + g * 16 + row16) * 64 + sw];
#pragma unroll
      for (int h = 0; h < 4; ++h)
        bf[h] = *(const short8*)&Bs[cur][(wn + h * 16 + row16) * 64 + sw];
#pragma unroll
      for (int g = 0; g < 4; ++g)
#pragma unroll
        for (int h = 0; h < 4; ++h)
          acc[g][h] = __builtin_amdgcn_mfma_f32_16x16x32_bf16(af[g], bf[h], acc[g][h], 0, 0, 0);
    }
    __builtin_amdgcn_s_barrier();   // reads of buf[cur] done before it is re-staged
  }
  asm volatile("s_waitcnt vmcnt(0)" ::: "memory");   // drain redundant last prefetch

  float* outp = nullptr; int Nout = 0, nb0; float wdq;
  if (mode == 1)      { outp = oQ;  Nout = 2048; nb0 = bx * 128;        wdq = fmaxf((float)sums[3] * INV_BIG,   1e-5f); }
  else if (bx < 16)   { outp = oQ;  Nout = 2048; nb0 = bx * 128;        wdq = fmaxf((float)sums[0] * INV_BIG,   1e-5f); }
  else if (bx < 20)   {             Nout = 512;  nb0 = (bx - 16) * 128; wdq = fmaxf((float)sums[1] * INV_SMALL, 1e-5f); }
  else if (bx < 24)   { outp = oV;  Nout = 512;  nb0 = (bx - 20) * 128; wdq = fmaxf((float)sums[2] * INV_SMALL, 1e-5f); }
  else                { outp = oQN; Nout = 2048; nb0 = (bx - 24) * 128; wdq = fmaxf((float)sums[4] * INV_BIG,   1e-5f); }

  if (mode == 0 && bx < 20) {
    // RoPE epilogue. head-relative d = (wn + h*16 + row16) & 63 = h*16 + row16.
#pragma unroll
    for (int g = 0; g < 4; ++g)
#pragma unroll
      for (int r = 0; r < 4; ++r) {
        int m = m0 + wm + g * 16 + q * 4 + r;
        float s = adq[m] * wdq;
        float2 cs0 = ropetab[m * 32 + row16];        // d = row16
        float2 cs1 = ropetab[m * 32 + 16 + row16];   // d = 16 + row16
        float v0 = acc[g][0][r] * s, v1 = acc[g][1][r] * s;
        float v2 = acc[g][2][r] * s, v3 = acc[g][3][r] * s;
        float o0 = v0 * cs0.x - v2 * cs0.y;
        float o2 = v2 * cs0.x + v0 * cs0.y;
        float o1 = v1 * cs1.x - v3 * cs1.y;
        float o3 = v3 * cs1.x + v1 * cs1.y;
        if (bx < 16) {   // Q: fp32
          size_t base = (size_t)m * Nout + nb0 + wn;
          outp[base + row16]      = o0;
          outp[base + 16 + row16] = o1;
          outp[base + 32 + row16] = o2;
          outp[base + 48 + row16] = o3;
        } else {
          // K: RN-bsplit into fragment-ordered hi/lo planes.
          // value o_h: key rr = m&63 (tile kt_ = m>>6), d = h*16 + row16.
          int hkv_ = (nb0 + wn) >> 6;
          int kt_ = m >> 6, rr = m & 63;
          size_t tb = ((size_t)(hkv_ * 16 + kt_)) * 4096;
          int lbase = (rr & 15) + ((row16 >> 3) << 4);
          int ntb = (rr >> 4) * 512 + (row16 & 7);
          unsigned short hi, lo; int ix;
          bsplit(o0, hi, lo); ix = ntb + (lbase     ) * 8;          oKhi[tb + ix] = hi; oKlo[tb + ix] = lo;
          bsplit(o1, hi, lo); ix = ntb + (lbase + 32) * 8;          oKhi[tb + ix] = hi; oKlo[tb + ix] = lo;
          bsplit(o2, hi, lo); ix = ntb + (lbase     ) * 8 + 2048;   oKhi[tb + ix] = hi; oKlo[tb + ix] = lo;
          bsplit(o3, hi, lo); ix = ntb + (lbase + 32) * 8 + 2048;   oKhi[tb + ix] = hi; oKlo[tb + ix] = lo;
        }
      }
  } else {
#pragma unroll
    for (int g = 0; g < 4; ++g)
#pragma unroll
      for (int r = 0; r < 4; ++r) {
        int m = m0 + wm + g * 16 + q * 4 + r;
        float s = adq[m] * wdq;
#pragma unroll
        for (int h = 0; h < 4; ++h)
          outp[(size_t)m * Nout + nb0 + wn + h * 16 + row16] = acc[g][h][r] * s;
      }
  }
}

// ---------------------------------------------------------------------------
// O-projection GEMM, 64x64 tiles: grid 32x16 = 512 blocks (2/CU). Same DMA
// staging + counted-vmcnt double buffer.
__global__ __launch_bounds__(256) void k_gemm64(
    const unsigned short* __restrict__ Aq, const unsigned short* __restrict__ Bq,
    const float* __restrict__ adq, const double* __restrict__ sums,
    float* __restrict__ out) {
  __shared__ __attribute__((aligned(16))) unsigned short As[2][64 * 64];
  __shared__ __attribute__((aligned(16))) unsigned short Bs[2][64 * 64];
  const int t = threadIdx.x;
  const int lane = t & 63;
  const int row16 = lane & 15, q = lane >> 4;
  const int w = t >> 6;
  const int wm = (w >> 1) * 32, wn = (w & 1) * 32;
  const int nb0 = blockIdx.x * 64;
  const int m0 = blockIdx.y * 64;
  const int swr = row16 & 7;

  floatx4 acc[2][2];
#pragma unroll
  for (int g = 0; g < 2; ++g)
#pragma unroll
    for (int h = 0; h < 2; ++h) acc[g][h] = (floatx4){0.f, 0.f, 0.f, 0.f};

  auto stageAB = [&](int k0s, int b) {
#pragma unroll
    for (int i = 0; i < 2; ++i) {
      int c = t + 256 * i;
      int row = c >> 3, g8 = c & 7;
      int sa = (g8 ^ (row & 7)) * 8;
      gload16(Aq + (size_t)(m0 + row) * 2048 + k0s + sa, &As[b][w * 512 + i * 2048]);
      gload16(Bq + (size_t)(nb0 + row) * 2048 + k0s + sa, &Bs[b][w * 512 + i * 2048]);
    }
  };

  stageAB(0, 0);
  for (int k0 = 0; k0 < 2048; k0 += 64) {
    const int cur = (k0 >> 6) & 1;
    const int kn = (k0 + 64 < 2048) ? k0 + 64 : k0;
    stageAB(kn, cur ^ 1);
    asm volatile("s_waitcnt vmcnt(4)" ::: "memory");
    __builtin_amdgcn_s_barrier();
#pragma unroll
    for (int kk = 0; kk < 2; ++kk) {
      short8 af[2], bf[2];
      const int sw = ((kk * 4 + q) ^ swr) << 3;
#pragma unroll
      for (int g = 0; g < 2; ++g)
        af[g] = *(const short8*)&As[cur][(wm + g * 16 + row16) * 64 + sw];
#pragma unroll
      for (int h = 0; h < 2; ++h)
        bf[h] = *(const short8*)&Bs[cur][(wn + h * 16 + row16) * 64 + sw];
#pragma unroll
      for (int g = 0; g < 2; ++g)
#pragma unroll
        for (int h = 0; h < 2; ++h)
          acc[g][h] = __builtin_amdgcn_mfma_f32_16x16x32_bf16(af[g], bf[h], acc[g][h], 0, 0, 0);
    }
    __builtin_amdgcn_s_barrier();
  }
  asm volatile("s_waitcnt vmcnt(0)" ::: "memory");

  float wdq = fmaxf((float)sums[3] * INV_BIG, 1e-5f);
#pragma unroll
  for (int g = 0; g < 2; ++g)
#pragma unroll
    for (int r = 0; r < 4; ++r) {
      int m = m0 + wm + g * 16 + q * 4 + r;
      float s = adq[m] * wdq;
#pragma unroll
      for (int h = 0; h < 2; ++h)
        out[(size_t)m * 2048 + nb0 + wn + h * 16 + row16] = acc[g][h][r] * s;
    }
}

// ---------------------------------------------------------------------------
// Merged prep. All outputs are 8KB fragment-ordered ushort tile planes (see
// header comment) so attention loads fragments global->VGPR fully coalesced.
//   blocks [0,1024):    vtKB  (transpose kbv -> V^T, RN-bsplit hi/lo planes)
//   blocks [1024,1152): vtP   (transpose Vb  -> V^T, RN-bsplit hi/lo planes)
//   blocks >= 1152:     kbk   in-place tile split [key][d] -> [hi 8KB | lo 8KB]
__global__ __launch_bounds__(256) void k_prep(
    const float* __restrict__ kbv, const float* __restrict__ Vb,
    unsigned short* __restrict__ vtKBhi, unsigned short* __restrict__ vtPhi,
    float* __restrict__ kbk) {
  const int b = blockIdx.x;
  const int t = threadIdx.x;
  if (b >= 1152) {
    float* tile = kbk + (size_t)(b - 1152) * 4096;   // 64x64 f32 [key][d], contiguous
    float v[2][8];
#pragma unroll
    for (int u = 0; u < 2; ++u) {
      int task = t + 256 * u;            // 512 tasks: key r = task>>3, d-slot s = task&7
      int r = task >> 3, s = task & 7;
      *(float4*)&v[u][0] = *(const float4*)(tile + r * 64 + s * 8);
      *(float4*)&v[u][4] = *(const float4*)(tile + r * 64 + s * 8 + 4);
    }
    __syncthreads();                     // all reads before any in-place write
    unsigned short* up = (unsigned short*)tile;
#pragma unroll
    for (int u = 0; u < 2; ++u) {
      int task = t + 256 * u;
      int r = task >> 3, s = task & 7;   // element (key=r, d=s*8+j)
      union { unsigned short u16[8]; uint4 q; } hi, lo;
#pragma unroll
      for (int j = 0; j < 8; ++j) bsplit(v[u][j], hi.u16[j], lo.u16[j]);
      // K-frag: frag = (d>>5)*4 + (key>>4); lane = (key&15) + 16*((d&31)>>3); j = d&7
      size_t off = (size_t)(((s >> 2) * 4 + (r >> 4)) * 512 + ((r & 15) + ((s & 3) << 4)) * 8);
      *(uint4*)(up + off)        = hi.q;
      *(uint4*)(up + 4096 + off) = lo.q;
    }
    return;
  }
  __shared__ float Lf[64 * 65];
  const float* src; unsigned short *dhi, *dlo; int srcStride;
  if (b < 1024) {
    int h = b >> 5, kt = b & 31;
    src = kbv + ((size_t)h * cKB + kt * 64) * 64; srcStride = 64;
    dhi = vtKBhi + (size_t)b * 4096; dlo = dhi + 4194304;
  } else {
    int bb = b - 1024;
    int hkv = bb >> 4, kt = bb & 15;
    src = Vb + (size_t)(kt * 64) * 512 + hkv * 64; srcStride = 512;
    dhi = vtPhi + (size_t)bb * 4096; dlo = dhi + 524288;
  }
#pragma unroll
  for (int i = 0; i < 4; ++i) {
    int c = t + 256 * i;
    int row = c >> 4, c4 = (c & 15) * 4;       // row = key, col = d
    float4 x = *(const float4*)(src + (size_t)row * srcStride + c4);
    Lf[row * 65 + c4 + 0] = x.x;
    Lf[row * 65 + c4 + 1] = x.y;
    Lf[row * 65 + c4 + 2] = x.z;
    Lf[row * 65 + c4 + 3] = x.w;
  }
  __syncthreads();
#pragma unroll
  for (int u = 0; u < 2; ++u) {
    int task = t + 256 * u;                    // d = task>>3, key slot s = task&7
    int d = task >> 3, s = task & 7;           // element (d, key=s*8+j)
    union { unsigned short u16[8]; uint4 q; } hi, lo;
#pragma unroll
    for (int j = 0; j < 8; ++j) bsplit(Lf[(s * 8 + j) * 65 + d], hi.u16[j], lo.u16[j]);
    // V^T-frag: frag = (key>>5)*4 + (d>>4); lane = (d&15) + 16*((key&31)>>3); j = key&7
    size_t off = (size_t)(((s >> 2) * 4 + (d >> 4)) * 512 + ((d & 15) + ((s & 3) << 4)) * 8);
    *(uint4*)(dhi + off) = hi.q;
    *(uint4*)(dlo + off) = lo.q;
  }
}

// ---------------------------------------------------------------------------
// Split-bf16 MFMA flash attention, register-direct K + d-SPLIT PV:
// QK/softmax unchanged from r7 (wave owns 16 q rows, full K = 16 KB/wave).
// PV flipped: wave w computes O[all 64 q][its 16 d] from the block-level
// shared P (LDS) and only V^T's 16-d slice (4 KB/wave, was 16 KB).
// Per-wave L1 traffic 32->20 KB/tile; r7 measured 61 B/cyc/CU == L1 port
// saturation, so this is the binding-resource cut (keeps 2 waves/SIMD —
// r8 showed 1 wave/SIMD is latency-bound). Online-softmax rescale of the
// cross-wave acco rows uses a per-tile 64-float alpha broadcast via LDS;
// l is exchanged once at the epilogue.
__global__ __launch_bounds__(256, 2) void k_attn_mfma(
    const float* __restrict__ Qr, float* qnctx,
    const unsigned short* __restrict__ KPhi,    // prompt K planes, lo at +524288
    const unsigned short* __restrict__ kbkS,    // KB K tiles [h*32+kt][hi 4096 | lo 4096]
    const unsigned short* __restrict__ vtKBhi,  // KB V^T planes, lo at +4194304
    const unsigned short* __restrict__ vtPhi) { // prompt V^T planes, lo at +524288
  __shared__ __attribute__((aligned(16))) unsigned int Pbuf[64 * 68];   // block-level P
  __shared__ __attribute__((aligned(16))) float aex[64];                // alpha / l exchange

  const int t = threadIdx.x;
  const int lane = t & 63;
  const int col = lane & 15;
  const int quad = lane >> 4;
  const int w = t >> 6;
  const int h = blockIdx.x;
  const int q0 = blockIdx.y * 64;
  const int hkv = h >> 2;
  const float kbbias = 0.69314718055994531f;   // log(4096)-log(2048)
  const int fl = lane * 8;                     // fragment lane offset (ushorts)

  short8 qAh[2], qAl[2];   // kb_q (not rotated), this wave's 16 q rows
  short8 qBh[2], qBl[2];   // rotated prompt q
  {
#pragma unroll
    for (int kk = 0; kk < 2; ++kk) {
      const size_t off = (size_t)(q0 + w * 16 + col) * 2048 + h * 64 + kk * 32 + quad * 8;
      float4 a = *(const float4*)(qnctx + off);
      float4 b = *(const float4*)(qnctx + off + 4);
      float xs[8] = {a.x, a.y, a.z, a.w, b.x, b.y, b.z, b.w};
#pragma unroll
      for (int j = 0; j < 8; ++j) {
        unsigned short hi, lo;
        bsplit(xs[j] * 0.125f, hi, lo);   // fold 1/sqrt(64), exact
        qAh[kk][j] = (short)hi; qAl[kk][j] = (short)lo;
      }
      float4 c = *(const float4*)(Qr + off);
      float4 d = *(const float4*)(Qr + off + 4);
      float ys[8] = {c.x, c.y, c.z, c.w, d.x, d.y, d.z, d.w};
#pragma unroll
      for (int j = 0; j < 8; ++j) {
        unsigned short hi, lo;
        bsplit(ys[j] * 0.125f, hi, lo);
        qBh[kk][j] = (short)hi; qBl[kk][j] = (short)lo;
      }
    }
  }

  floatx4 acco[4];          // [g] -> O rows g*16+quad*4+r, cols d = w*16+col
  float m_[4], l_[4];       // this wave's own 16 q rows
#pragma unroll
  for (int g = 0; g < 4; ++g) acco[g] = (floatx4){0.f, 0.f, 0.f, 0.f};
#pragma unroll
  for (int r = 0; r < 4; ++r) { m_[r] = -3.0e38f; l_[r] = 0.f; }

  const int ntiles = 32 + (q0 >> 6) + 1;

  short8 kh[2][4], kl[2][4];   // full K tile fragments (hi/lo)
  short8 vh[2], vl[2];         // V^T d-slice fragments (this wave's 16 d)

  auto loadK = [&](int kt2) {
    const unsigned short *ph, *pl;
    if (kt2 < 32) { const size_t tk = (size_t)(h * 32 + kt2);
                    ph = kbkS + tk * 8192; pl = ph + 4096; }
    else          { const size_t tk = (size_t)(hkv * 16 + (kt2 - 32));
                    ph = KPhi + tk * 4096; pl = ph + 524288; }
#pragma unroll
    for (int kk = 0; kk < 2; ++kk)
#pragma unroll
      for (int nt = 0; nt < 4; ++nt) {
        kh[kk][nt] = *(const short8*)(ph + (kk * 4 + nt) * 512 + fl);
        kl[kk][nt] = *(const short8*)(pl + (kk * 4 + nt) * 512 + fl);
      }
  };
  auto loadV = [&](int kt2) {
    const unsigned short *ph, *pl;
    if (kt2 < 32) { const size_t tk = (size_t)(h * 32 + kt2);
                    ph = vtKBhi + tk * 4096; pl = ph + 4194304; }
    else          { const size_t tk = (size_t)(hkv * 16 + (kt2 - 32));
                    ph = vtPhi + tk * 4096; pl = ph + 524288; }
#pragma unroll
    for (int kk = 0; kk < 2; ++kk) {
      vh[kk] = *(const short8*)(ph + (kk * 4 + w) * 512 + fl);
      vl[kk] = *(const short8*)(pl + (kk * 4 + w) * 512 + fl);
    }
  };

  loadK(0);   // prologue

  for (int kt = 0; kt < ntiles; ++kt) {
    const bool isKB = kt < 32;
    loadV(kt);                          // in flight during QK+softmax
    // Barrier #1: convergence + Pbuf/aex WAR separator (raw: K/V stay in flight).
    __builtin_amdgcn_s_barrier();

    floatx4 accs[4];
#pragma unroll
    for (int nt = 0; nt < 4; ++nt) accs[nt] = (floatx4){0.f, 0.f, 0.f, 0.f};
    if (isKB) {
#pragma unroll
      for (int kk = 0; kk < 2; ++kk)
#pragma unroll
        for (int nt = 0; nt < 4; ++nt) {
          accs[nt] = __builtin_amdgcn_mfma_f32_16x16x32_bf16(qAh[kk], kh[kk][nt], accs[nt], 0, 0, 0);
          accs[nt] = __builtin_amdgcn_mfma_f32_16x16x32_bf16(qAl[kk], kh[kk][nt], accs[nt], 0, 0, 0);
          accs[nt] = __builtin_amdgcn_mfma_f32_16x16x32_bf16(qAh[kk], kl[kk][nt], accs[nt], 0, 0, 0);
        }
    } else {
#pragma unroll
      for (int kk = 0; kk < 2; ++kk)
#pragma unroll
        for (int nt = 0; nt < 4; ++nt) {
          accs[nt] = __builtin_amdgcn_mfma_f32_16x16x32_bf16(qBh[kk], kh[kk][nt], accs[nt], 0, 0, 0);
          accs[nt] = __builtin_amdgcn_mfma_f32_16x16x32_bf16(qBl[kk], kh[kk][nt], accs[nt], 0, 0, 0);
          accs[nt] = __builtin_amdgcn_mfma_f32_16x16x32_bf16(qBh[kk], kl[kk][nt], accs[nt], 0, 0, 0);
        }
    }

    // Bias/mask: KB tiles = uniform bias; prompt non-diagonal = none; only the
    // final (diagonal) tile needs the causal mask.
    float sv[4][4];
    if (isKB) {
#pragma unroll
      for (int nt = 0; nt < 4; ++nt)
#pragma unroll
        for (int r = 0; r < 4; ++r) sv[nt][r] = accs[nt][r] + kbbias;
    } else if (kt < ntiles - 1) {
#pragma unroll
      for (int nt = 0; nt < 4; ++nt)
#pragma unroll
        for (int r = 0; r < 4; ++r) sv[nt][r] = accs[nt][r];
    } else {
#pragma unroll
      for (int nt = 0; nt < 4; ++nt) {
        int kl_ = nt * 16 + col;
#pragma unroll
        for (int r = 0; r < 4; ++r) {
          int ql_ = w * 16 + quad * 4 + r;
          sv[nt][r] = accs[nt][r] + ((kl_ <= ql_) ? 0.0f : -1e9f);
        }
      }
    }
    float alpha_[4];
#pragma unroll
    for (int r = 0; r < 4; ++r) {
      float rmax = fmaxf(fmaxf(sv[0][r], sv[1][r]), fmaxf(sv[2][r], sv[3][r]));
#pragma unroll
      for (int off = 8; off; off >>= 1) rmax = fmaxf(rmax, __shfl_xor(rmax, off));
      float mnew = fmaxf(m_[r], rmax);
      float alpha = __expf(m_[r] - mnew);
      float psum = 0.f;
#pragma unroll
      for (int nt = 0; nt < 4; ++nt) {
        float p = __expf(sv[nt][r] - mnew);
        sv[nt][r] = p;
        psum += p;
      }
#pragma unroll
      for (int off = 8; off; off >>= 1) psum += __shfl_xor(psum, off);
      l_[r] = l_[r] * alpha + psum;
      m_[r] = mnew;
      alpha_[r] = alpha;
    }

    // Prefetch next tile's K (WAR on kh/kl keeps these after the QK MFMAs;
    // in flight during P-pack + PV). Clamped redundant load on last tile.
    loadK(kt + 1 < ntiles ? kt + 1 : kt);

    // P truncation split -> packed hi|lo<<16, written to this wave's 16 rows
    // of the BLOCK-level Pbuf; alpha broadcast for the cross-wave O rescale.
#pragma unroll
    for (int nt = 0; nt < 4; ++nt)
#pragma unroll
      for (int r = 0; r < 4; ++r) {
        unsigned xb = __float_as_uint(sv[nt][r]);
        float hf = __uint_as_float(xb & 0xffff0000u);
        unsigned db = __float_as_uint(sv[nt][r] - hf);
        Pbuf[(w * 16 + quad * 4 + r) * 68 + nt * 16 + col] = (xb >> 16) | (db & 0xffff0000u);
      }
    if (col < 4) aex[w * 16 + quad * 4 + col] = alpha_[col];

    // Barrier #2: P/alpha visible block-wide (drain LDS writes only; the K/V
    // prefetch stays in flight across the barrier).
    asm volatile("s_waitcnt lgkmcnt(0)" ::: "memory");
    __builtin_amdgcn_s_barrier();

    // Rescale O rows (all 64, alphas from every wave) then PV over the full P.
#pragma unroll
    for (int g = 0; g < 4; ++g) {
      float4 ar = *(const float4*)&aex[g * 16 + quad * 4];
      acco[g][0] *= ar.x; acco[g][1] *= ar.y; acco[g][2] *= ar.z; acco[g][3] *= ar.w;
    }
#pragma unroll
    for (int kk = 0; kk < 2; ++kk)
#pragma unroll
      for (int g = 0; g < 4; ++g) {
        uint4 pa = *(const uint4*)&Pbuf[(g * 16 + col) * 68 + kk * 32 + quad * 8];
        uint4 pb = *(const uint4*)&Pbuf[(g * 16 + col) * 68 + kk * 32 + quad * 8 + 4];
        union { unsigned int u[4]; short8 s; } uh, ul;
        uh.u[0] = (pa.x & 0xffffu) | (pa.y << 16);
        uh.u[1] = (pa.z & 0xffffu) | (pa.w << 16);
        uh.u[2] = (pb.x & 0xffffu) | (pb.y << 16);
        uh.u[3] = (pb.z & 0xffffu) | (pb.w << 16);
        ul.u[0] = (pa.x >> 16) | (pa.y & 0xffff0000u);
        ul.u[1] = (pa.z >> 16) | (pa.w & 0xffff0000u);
        ul.u[2] = (pb.x >> 16) | (pb.y & 0xffff0000u);
        ul.u[3] = (pb.z >> 16) | (pb.w & 0xffff0000u);
        short8 ph8 = uh.s, pl8 = ul.s;
        acco[g] = __builtin_amdgcn_mfma_f32_16x16x32_bf16(ph8, vh[kk], acco[g], 0, 0, 0);
        acco[g] = __builtin_amdgcn_mfma_f32_16x16x32_bf16(pl8, vh[kk], acco[g], 0, 0, 0);
        acco[g] = __builtin_amdgcn_mfma_f32_16x16x32_bf16(ph8, vl[kk], acco[g], 0, 0, 0);
      }
  }

  // Epilogue: exchange l (once), then write O[all 64 q][this wave's 16 d].
  __syncthreads();
  if (col < 4) aex[w * 16 + quad * 4 + col] = l_[col];
  __syncthreads();
#pragma unroll
  for (int g = 0; g < 4; ++g) {
    float4 lr = *(const float4*)&aex[g * 16 + quad * 4];
    float4 li = {1.0f / lr.x, 1.0f / lr.y, 1.0f / lr.z, 1.0f / lr.w};
#pragma unroll
    for (int r = 0; r < 4; ++r)
      qnctx[(size_t)(q0 + g * 16 + quad * 4 + r) * 2048 + h * 64 + w * 16 + col] =
          acco[g][r] * ((const float*)&li)[r];
  }
}

// ---------------------------------------------------------------------------
extern "C" void kernel_launch(void* const* d_in, const int* in_sizes, int n_in,
                              void* d_out, int out_size, void* d_ws, size_t ws_size,
                              hipStream_t stream) {
  (void)in_sizes; (void)n_in; (void)out_size; (void)ws_size;
  const float* hidden = (const float*)d_in[0];
  float* kbk = (float*)d_in[2];              // tile-split in place (restored each launch)
  const float* kbv = (const float*)d_in[3];
  const float* Wq  = (const float*)d_in[4];
  const float* Wk  = (const float*)d_in[5];
  const float* Wv  = (const float*)d_in[6];
  const float* Wo  = (const float*)d_in[7];
  const float* Wqn = (const float*)d_in[8];
  const int*   pos = (const int*)d_in[9];

  char* ws = (char*)d_ws;
  double* sums = (double*)(ws + WS_SUMS);
  float* dq1 = (float*)(ws + WS_DQ1);
  float* dq2 = (float*)(ws + WS_DQ2);
  unsigned short* xq   = (unsigned short*)(ws + WS_XQ);
  unsigned short* wall = (unsigned short*)(ws + WS_WALL);
  unsigned short* vtKBhi = (unsigned short*)(ws + WS_WALL);              // after GEMM
  unsigned short* vtPhi  = (unsigned short*)(ws + WS_WALL + 16777216);   // after GEMM
  unsigned short* wqo  = (unsigned short*)(ws + WS_QB);                  // after attn
  float* Qb  = (float*)(ws + WS_QB);
  unsigned short* KPhi = (unsigned short*)(ws + WS_KB);                  // prompt K hi
  unsigned short* KPlo = KPhi + 524288;                                  // prompt K lo
  float* Vb  = (float*)(ws + WS_VB);
  float* QNC = (float*)(ws + WS_QN);   // kb_q, then CTX
  float2* ropetab = (float2*)(ws + WS_ROPET);

  hipMemsetAsync(sums, 0, 64, stream);

  k_ropetab<<<128, 256, 0, stream>>>(pos, ropetab);
  k_abssum5<<<dim3(128, 5), 256, 0, stream>>>(Wq, Wk, Wv, Wo, Wqn, sums);
  k_wquant4<<<10240, 256, 0, stream>>>(Wq, Wk, Wv, Wqn, wall, sums);
  k_aquant<<<cQ, 256, 0, stream>>>(hidden, xq, dq1, cH);

  // Fused Q/K/V/QN GEMM with RoPE epilogue: 128x128 tiles, grid 40x8
  k_gemm_mfma<<<dim3(40, 8), 256, 0, stream>>>(xq, wall, dq1, sums, ropetab,
                                               Qb, KPhi, KPlo, Vb, QNC, 0);

  // V transposes (1152 blocks) + kbk in-place tile split (1024 blocks)
  k_prep<<<1152 + 1024, 256, 0, stream>>>(kbv, Vb, vtKBhi, vtPhi, kbk);

  k_attn_mfma<<<dim3(cNH, cQ / 64), 256, 0, stream>>>(
      Qb, QNC, KPhi, (const unsigned short*)kbk, vtKBhi, vtPhi);

  k_wquant<<<4096, 256, 0, stream>>>(Wo, wqo, sums + 3, INV_BIG);
  k_aquant<<<cQ, 256, 0, stream>>>(QNC, xq, dq2, cH);

  // O projection: 64x64 tiles, grid 32x16 = 512 blocks (2/CU)
  k_gemm64<<<dim3(32, 16), 256, 0, stream>>>(xq, wqo, dq2, sums, (float*)d_out);
}

// Round 10
// 380.793 us; speedup vs baseline: 1.0964x; 1.0267x over previous
//
#include <hip/hip_runtime.h>
#include <hip/hip_bf16.h>
#include <stdint.h>
#include <math.h>

// Problem constants (B=1)
#define cH    2048
#define cQ    1024
#define cNH   32
#define cNKV  8
#define cKB   2048

#define INV_BIG   (1.0f/4194304.0f)   // 1/(2048*2048)
#define INV_SMALL (1.0f/1048576.0f)   // 1/(512*2048)

// ---------------------------------------------------------------------------
// Workspace layout (bytes). Total = 46,407,936 (<= proven 48,242,944).
#define WS_SUMS 0           // 8 doubles (5 used)
#define WS_DQ1  256         // 1024 f32
#define WS_DQ2  4352        // 1024 f32
#define WS_XQ   8448        // 1024x2048 bf16 (xq1; reused as xq2 after attention)
#define WS_WALL 4202752     // 5120x2048 bf16 weights; DEAD after fused GEMM ->
                            //   vtKBhi 8MB frag-tiles [h*32+kt], vtKBlo at +8MB,
                            //   vtPhi 1MB frag-tiles [hkv*16+kt] at +16MB, vtPlo +17MB
#define WS_QB   25174272    // 1024x2048 f32 rotated q; reused as wqo after attn
#define WS_KB   33562880    // prompt K planes: KPhi 1MB frag-tiles, KPlo +1MB
#define WS_VB   35660032    // 1024x512 f32 v (source for vtrans)
#define WS_QN   37757184    // 1024x2048 f32 kb_q; reused as CTX (same rows+cols per block)
#define WS_ROPET 46145792   // 1024x32 float2 cos/sin table (262,144 B)

// Fragment-ordered 8KB tile plane: fragment f = kk*4 + nt (kk = inner-dim>>5,
// nt = outer-dim>>4); within fragment, lane = (outer&15) + 16*((inner&31)>>3),
// elem j = inner&7. One fragment = 64 lanes x 16B = 1KB, loads coalesced.

using short8  = __attribute__((ext_vector_type(8))) short;
using floatx4 = __attribute__((ext_vector_type(4))) float;

__device__ __forceinline__ void bsplit(float x, unsigned short& hi, unsigned short& lo) {
  __hip_bfloat16 h = __float2bfloat16(x);          // RN
  float hf = __bfloat162float(h);
  __hip_bfloat16 l = __float2bfloat16(x - hf);     // exact residual, RN again
  hi = *(unsigned short*)&h;
  lo = *(unsigned short*)&l;
}

__device__ __forceinline__ unsigned short tern(float v, float ws) {
  float q = rintf(v * ws);
  q = fminf(fmaxf(q, -1.0f), 1.0f);
  return (unsigned short)(__float_as_uint(q) >> 16);
}

// Async 16B global->LDS (direct-to-shared DMA; dest = wave-uniform base + lane*16).
__device__ __forceinline__ void gload16(const void* g, void* l) {
  __builtin_amdgcn_global_load_lds((const __attribute__((address_space(1))) void*)g,
                                   (__attribute__((address_space(3))) void*)l, 16, 0, 0);
}

// ---------------------------------------------------------------------------
// RoPE cos/sin table: 1024 positions x 32 freqs, fp64 math once.
__global__ void k_ropetab(const int* __restrict__ pos, float2* __restrict__ tab) {
  int i = blockIdx.x * 256 + threadIdx.x;   // 32768
  int t = i >> 5, d = i & 31;
  double p = (double)pos[t];
  double ang = p * pow(10000.0, -(double)d / 32.0);
  tab[i] = make_float2((float)cos(ang), (float)sin(ang));
}

// ---------------------------------------------------------------------------
__global__ void k_abssum5(const float* __restrict__ w0, const float* __restrict__ w1,
                          const float* __restrict__ w2, const float* __restrict__ w3,
                          const float* __restrict__ w4, double* __restrict__ out) {
  __shared__ double red[256];
  const int seg = blockIdx.y;
  const float* w = seg == 0 ? w0 : seg == 1 ? w1 : seg == 2 ? w2 : seg == 3 ? w3 : w4;
  const int n4 = ((seg == 1 || seg == 2) ? 512 * 2048 : 2048 * 2048) / 4;
  double s = 0.0;
  for (int i = blockIdx.x * 256 + threadIdx.x; i < n4; i += gridDim.x * 256) {
    float4 x = *(const float4*)(w + (size_t)i * 4);
    s += (double)fabsf(x.x) + (double)fabsf(x.y) + (double)fabsf(x.z) + (double)fabsf(x.w);
  }
  red[threadIdx.x] = s;
  __syncthreads();
  for (int o = 128; o > 0; o >>= 1) {
    if ((int)threadIdx.x < o) red[threadIdx.x] += red[threadIdx.x + o];
    __syncthreads();
  }
  if (threadIdx.x == 0) atomicAdd(out + seg, red[0]);
}

// Fused ternary quant of Wq/Wk/Wv/Wqn (4 elems/thread; segment bounds are /4).
__global__ void k_wquant4(const float* __restrict__ Wq, const float* __restrict__ Wk,
                          const float* __restrict__ Wv, const float* __restrict__ Wqn,
                          unsigned short* __restrict__ wall, const double* __restrict__ sums) {
  size_t i = ((size_t)blockIdx.x * 256 + threadIdx.x) * 4;   // 0 .. 10485756
  const float* src; size_t off; double s; float inv;
  if (i < 4194304)      { src = Wq;  off = 0;       s = sums[0]; inv = INV_BIG; }
  else if (i < 5242880) { src = Wk;  off = 4194304; s = sums[1]; inv = INV_SMALL; }
  else if (i < 6291456) { src = Wv;  off = 5242880; s = sums[2]; inv = INV_SMALL; }
  else                  { src = Wqn; off = 6291456; s = sums[4]; inv = INV_BIG; }
  float ws = 1.0f / fmaxf((float)s * inv, 1e-5f);
  float4 x = *(const float4*)(src + (i - off));
  ushort4 o;
  o.x = tern(x.x, ws); o.y = tern(x.y, ws); o.z = tern(x.z, ws); o.w = tern(x.w, ws);
  *(ushort4*)(wall + i) = o;
}

// Single-weight ternary quant (Wo), 4 elems/thread.
__global__ void k_wquant(const float* __restrict__ w, unsigned short* __restrict__ wq,
                         const double* __restrict__ sum, float inv_n) {
  size_t i = ((size_t)blockIdx.x * 256 + threadIdx.x) * 4;
  float ws = 1.0f / fmaxf((float)(*sum) * inv_n, 1e-5f);
  float4 x = *(const float4*)(w + i);
  ushort4 o;
  o.x = tern(x.x, ws); o.y = tern(x.y, ws); o.z = tern(x.z, ws); o.w = tern(x.w, ws);
  *(ushort4*)(wq + i) = o;
}

// Per-token int8 absmax activation quant -> bf16 integer values (float4 path).
__global__ void k_aquant(const float* __restrict__ x, unsigned short* __restrict__ xq,
                         float* __restrict__ dq, int K) {
  int t = blockIdx.x;
  const float4* xr = (const float4*)(x + (size_t)t * K);
  const int K4 = K / 4;
  __shared__ float red[256];
  float m = 0.0f;
  for (int i = threadIdx.x; i < K4; i += 256) {
    float4 v = xr[i];
    m = fmaxf(m, fmaxf(fmaxf(fabsf(v.x), fabsf(v.y)), fmaxf(fabsf(v.z), fabsf(v.w))));
  }
  red[threadIdx.x] = m;
  __syncthreads();
  for (int o = 128; o > 0; o >>= 1) {
    if ((int)threadIdx.x < o) red[threadIdx.x] = fmaxf(red[threadIdx.x], red[threadIdx.x + o]);
    __syncthreads();
  }
  float amax = fmaxf(red[0], 1e-5f);
  float as = 127.0f / amax;
  ushort4* xo = (ushort4*)(xq + (size_t)t * K);
  for (int i = threadIdx.x; i < K4; i += 256) {
    float4 v = xr[i];
    ushort4 o;
    float q;
    q = fminf(fmaxf(rintf(v.x * as), -128.0f), 127.0f); o.x = (unsigned short)(__float_as_uint(q) >> 16);
    q = fminf(fmaxf(rintf(v.y * as), -128.0f), 127.0f); o.y = (unsigned short)(__float_as_uint(q) >> 16);
    q = fminf(fmaxf(rintf(v.z * as), -128.0f), 127.0f); o.z = (unsigned short)(__float_as_uint(q) >> 16);
    q = fminf(fmaxf(rintf(v.w * as), -128.0f), 127.0f); o.w = (unsigned short)(__float_as_uint(q) >> 16);
    xo[i] = o;
  }
  if (threadIdx.x == 0) dq[t] = amax / 127.0f;
}

// ---------------------------------------------------------------------------
// Unified bf16-MFMA BitLinear GEMM, 64x64 tiles, 4 waves x (16 M-rows, full
// 64 N-cols) each — keeps the RoPE pair (d, d+32) in-thread (acc[h]/acc[h+2]).
// QKV grid 80x16 = 1280 blocks = exactly 5/CU (the old 128-tile grid was 320
// blocks on 256 CUs: a straggler round with 75% of the GPU idle). LDS 32KB x
// 5 blocks = 160KB exact fit. DMA staging + counted-vmcnt double buffer (r7).
// mode 0: fused QKV+QN with RoPE/K-split epilogue; mode 1: O-projection.
__global__ __launch_bounds__(256) void k_gemm64u(
    const unsigned short* __restrict__ Aq, const unsigned short* __restrict__ Ball,
    const float* __restrict__ adq, const double* __restrict__ sums,
    const float2* __restrict__ ropetab,
    float* __restrict__ oQ, unsigned short* __restrict__ oKhi,
    unsigned short* __restrict__ oKlo,
    float* __restrict__ oV, float* __restrict__ oQN, int mode) {
  __shared__ __attribute__((aligned(16))) unsigned short As[2][64 * 64];
  __shared__ __attribute__((aligned(16))) unsigned short Bs[2][64 * 64];
  const int t = threadIdx.x;
  const int lane = t & 63;
  const int row16 = lane & 15, q = lane >> 4;
  const int w = t >> 6;
  const int bx = blockIdx.x;
  const int m0 = blockIdx.y * 64;
  const unsigned short* Bp = Ball + (size_t)bx * 64 * 2048;
  const int swr = row16 & 7;                 // fragment-read XOR key

  floatx4 acc[4];
#pragma unroll
  for (int h = 0; h < 4; ++h) acc[h] = (floatx4){0.f, 0.f, 0.f, 0.f};

  auto stageAB = [&](int k0s, int b) {
#pragma unroll
    for (int i = 0; i < 2; ++i) {
      int c = t + 256 * i;
      int row = c >> 3, g8 = c & 7;
      int sa = (g8 ^ (row & 7)) * 8;         // source col slot swizzle
      gload16(Aq + (size_t)(m0 + row) * 2048 + k0s + sa, &As[b][w * 512 + i * 2048]);
      gload16(Bp + (size_t)row * 2048 + k0s + sa, &Bs[b][w * 512 + i * 2048]);
    }
  };

  stageAB(0, 0);   // prologue: 4 DMA outstanding
  for (int k0 = 0; k0 < 2048; k0 += 64) {
    const int cur = (k0 >> 6) & 1;
    const int kn = (k0 + 64 < 2048) ? k0 + 64 : k0;   // clamped redundant last
    stageAB(kn, cur ^ 1);                             // +4 -> 8 outstanding
    asm volatile("s_waitcnt vmcnt(4)" ::: "memory");  // wait current tile's 4
    __builtin_amdgcn_s_barrier();
#pragma unroll
    for (int kk = 0; kk < 2; ++kk) {
      short8 af, bf[4];
      const int sw = ((kk * 4 + q) ^ swr) << 3;
      af = *(const short8*)&As[cur][(w * 16 + row16) * 64 + sw];
#pragma unroll
      for (int h = 0; h < 4; ++h)
        bf[h] = *(const short8*)&Bs[cur][(h * 16 + row16) * 64 + sw];
#pragma unroll
      for (int h = 0; h < 4; ++h)
        acc[h] = __builtin_amdgcn_mfma_f32_16x16x32_bf16(af, bf[h], acc[h], 0, 0, 0);
    }
    __builtin_amdgcn_s_barrier();   // reads of buf[cur] done before it is re-staged
  }
  asm volatile("s_waitcnt vmcnt(0)" ::: "memory");   // drain redundant last prefetch

  // Segment decode. QKV (mode 0): bx<32 Q | 32..39 K | 40..47 V | 48..79 QN.
  float* outp = nullptr; int Nout = 0, nb0; float wdq;
  if (mode == 1)      { outp = oQ;  Nout = 2048; nb0 = bx * 64;        wdq = fmaxf((float)sums[3] * INV_BIG,   1e-5f); }
  else if (bx < 32)   { outp = oQ;  Nout = 2048; nb0 = bx * 64;        wdq = fmaxf((float)sums[0] * INV_BIG,   1e-5f); }
  else if (bx < 40)   {             Nout = 512;  nb0 = (bx - 32) * 64; wdq = fmaxf((float)sums[1] * INV_SMALL, 1e-5f); }
  else if (bx < 48)   { outp = oV;  Nout = 512;  nb0 = (bx - 40) * 64; wdq = fmaxf((float)sums[2] * INV_SMALL, 1e-5f); }
  else                { outp = oQN; Nout = 2048; nb0 = (bx - 48) * 64; wdq = fmaxf((float)sums[4] * INV_BIG,   1e-5f); }

  if (mode == 0 && bx < 40) {
    // RoPE epilogue. nb0 is 64-aligned -> head-relative d = h*16 + row16;
    // pairs (d, d+32) = (acc[0],acc[2]) and (acc[1],acc[3]) in-thread.
#pragma unroll
    for (int r = 0; r < 4; ++r) {
      int m = m0 + w * 16 + q * 4 + r;
      float s = adq[m] * wdq;
      float2 cs0 = ropetab[m * 32 + row16];        // d = row16
      float2 cs1 = ropetab[m * 32 + 16 + row16];   // d = 16 + row16
      float v0 = acc[0][r] * s, v1 = acc[1][r] * s;
      float v2 = acc[2][r] * s, v3 = acc[3][r] * s;
      float o0 = v0 * cs0.x - v2 * cs0.y;
      float o2 = v2 * cs0.x + v0 * cs0.y;
      float o1 = v1 * cs1.x - v3 * cs1.y;
      float o3 = v3 * cs1.x + v1 * cs1.y;
      if (bx < 32) {   // Q: fp32
        size_t base = (size_t)m * 2048 + nb0;
        outp[base + row16]      = o0;
        outp[base + 16 + row16] = o1;
        outp[base + 32 + row16] = o2;
        outp[base + 48 + row16] = o3;
      } else {
        // K: RN-bsplit into fragment-ordered hi/lo planes.
        // value o_h: key rr = m&63 (tile kt_ = m>>6), d = h*16 + row16.
        int hkv_ = bx - 32;
        int kt_ = m >> 6, rr = m & 63;
        size_t tb = ((size_t)(hkv_ * 16 + kt_)) * 4096;
        int lbase = (rr & 15) + ((row16 >> 3) << 4);
        int ntb = (rr >> 4) * 512 + (row16 & 7);
        unsigned short hi, lo; int ix;
        bsplit(o0, hi, lo); ix = ntb + (lbase     ) * 8;          oKhi[tb + ix] = hi; oKlo[tb + ix] = lo;
        bsplit(o1, hi, lo); ix = ntb + (lbase + 32) * 8;          oKhi[tb + ix] = hi; oKlo[tb + ix] = lo;
        bsplit(o2, hi, lo); ix = ntb + (lbase     ) * 8 + 2048;   oKhi[tb + ix] = hi; oKlo[tb + ix] = lo;
        bsplit(o3, hi, lo); ix = ntb + (lbase + 32) * 8 + 2048;   oKhi[tb + ix] = hi; oKlo[tb + ix] = lo;
      }
    }
  } else {
#pragma unroll
    for (int r = 0; r < 4; ++r) {
      int m = m0 + w * 16 + q * 4 + r;
      float s = adq[m] * wdq;
#pragma unroll
      for (int h = 0; h < 4; ++h)
        outp[(size_t)m * Nout + nb0 + h * 16 + row16] = acc[h][r] * s;
    }
  }
}

// ---------------------------------------------------------------------------
// Merged prep. All outputs are 8KB fragment-ordered ushort tile planes (see
// header comment) so attention loads fragments global->VGPR fully coalesced.
//   blocks [0,1024):    vtKB  (transpose kbv -> V^T, RN-bsplit hi/lo planes)
//   blocks [1024,1152): vtP   (transpose Vb  -> V^T, RN-bsplit hi/lo planes)
//   blocks >= 1152:     kbk   in-place tile split [key][d] -> [hi 8KB | lo 8KB]
__global__ __launch_bounds__(256) void k_prep(
    const float* __restrict__ kbv, const float* __restrict__ Vb,
    unsigned short* __restrict__ vtKBhi, unsigned short* __restrict__ vtPhi,
    float* __restrict__ kbk) {
  const int b = blockIdx.x;
  const int t = threadIdx.x;
  if (b >= 1152) {
    float* tile = kbk + (size_t)(b - 1152) * 4096;   // 64x64 f32 [key][d], contiguous
    float v[2][8];
#pragma unroll
    for (int u = 0; u < 2; ++u) {
      int task = t + 256 * u;            // 512 tasks: key r = task>>3, d-slot s = task&7
      int r = task >> 3, s = task & 7;
      *(float4*)&v[u][0] = *(const float4*)(tile + r * 64 + s * 8);
      *(float4*)&v[u][4] = *(const float4*)(tile + r * 64 + s * 8 + 4);
    }
    __syncthreads();                     // all reads before any in-place write
    unsigned short* up = (unsigned short*)tile;
#pragma unroll
    for (int u = 0; u < 2; ++u) {
      int task = t + 256 * u;
      int r = task >> 3, s = task & 7;   // element (key=r, d=s*8+j)
      union { unsigned short u16[8]; uint4 q; } hi, lo;
#pragma unroll
      for (int j = 0; j < 8; ++j) bsplit(v[u][j], hi.u16[j], lo.u16[j]);
      // K-frag: frag = (d>>5)*4 + (key>>4); lane = (key&15) + 16*((d&31)>>3); j = d&7
      size_t off = (size_t)(((s >> 2) * 4 + (r >> 4)) * 512 + ((r & 15) + ((s & 3) << 4)) * 8);
      *(uint4*)(up + off)        = hi.q;
      *(uint4*)(up + 4096 + off) = lo.q;
    }
    return;
  }
  __shared__ float Lf[64 * 65];
  const float* src; unsigned short *dhi, *dlo; int srcStride;
  if (b < 1024) {
    int h = b >> 5, kt = b & 31;
    src = kbv + ((size_t)h * cKB + kt * 64) * 64; srcStride = 64;
    dhi = vtKBhi + (size_t)b * 4096; dlo = dhi + 4194304;
  } else {
    int bb = b - 1024;
    int hkv = bb >> 4, kt = bb & 15;
    src = Vb + (size_t)(kt * 64) * 512 + hkv * 64; srcStride = 512;
    dhi = vtPhi + (size_t)bb * 4096; dlo = dhi + 524288;
  }
#pragma unroll
  for (int i = 0; i < 4; ++i) {
    int c = t + 256 * i;
    int row = c >> 4, c4 = (c & 15) * 4;       // row = key, col = d
    float4 x = *(const float4*)(src + (size_t)row * srcStride + c4);
    Lf[row * 65 + c4 + 0] = x.x;
    Lf[row * 65 + c4 + 1] = x.y;
    Lf[row * 65 + c4 + 2] = x.z;
    Lf[row * 65 + c4 + 3] = x.w;
  }
  __syncthreads();
#pragma unroll
  for (int u = 0; u < 2; ++u) {
    int task = t + 256 * u;                    // d = task>>3, key slot s = task&7
    int d = task >> 3, s = task & 7;           // element (d, key=s*8+j)
    union { unsigned short u16[8]; uint4 q; } hi, lo;
#pragma unroll
    for (int j = 0; j < 8; ++j) bsplit(Lf[(s * 8 + j) * 65 + d], hi.u16[j], lo.u16[j]);
    // V^T-frag: frag = (key>>5)*4 + (d>>4); lane = (d&15) + 16*((key&31)>>3); j = key&7
    size_t off = (size_t)(((s >> 2) * 4 + (d >> 4)) * 512 + ((d & 15) + ((s & 3) << 4)) * 8);
    *(uint4*)(dhi + off) = hi.q;
    *(uint4*)(dlo + off) = lo.q;
  }
}

// ---------------------------------------------------------------------------
// Split-bf16 MFMA flash attention, REGISTER-DIRECT K/V — exact r7 structure
// (the measured equilibrium: 512 blocks, 2/CU, 2 waves/SIMD; all six
// structural variants tried land at >= this). Only addition: s_setprio(1)
// around the MFMA clusters (T5 — two independent blocks/CU at different
// phases is the m191-positive regime).
__global__ __launch_bounds__(256, 2) void k_attn_mfma(
    const float* __restrict__ Qr, float* qnctx,
    const unsigned short* __restrict__ KPhi,    // prompt K planes, lo at +524288
    const unsigned short* __restrict__ kbkS,    // KB K tiles [h*32+kt][hi 4096 | lo 4096]
    const unsigned short* __restrict__ vtKBhi,  // KB V^T planes, lo at +4194304
    const unsigned short* __restrict__ vtPhi) { // prompt V^T planes, lo at +524288
  __shared__ __attribute__((aligned(16))) unsigned int Pbuf[4][16 * 68];   // per-wave

  const int t = threadIdx.x;
  const int lane = t & 63;
  const int col = lane & 15;
  const int quad = lane >> 4;
  const int w = t >> 6;
  const int h = blockIdx.x;
  const int q0 = blockIdx.y * 64;
  const int hkv = h >> 2;
  const float kbbias = 0.69314718055994531f;   // log(4096)-log(2048)
  unsigned int* Pw = &Pbuf[w][0];
  const int fl = lane * 8;                     // fragment lane offset (ushorts)

  short8 qAh[2], qAl[2];   // kb_q (not rotated)
  short8 qBh[2], qBl[2];   // rotated prompt q
  {
#pragma unroll
    for (int kk = 0; kk < 2; ++kk) {
      const size_t off = (size_t)(q0 + w * 16 + col) * 2048 + h * 64 + kk * 32 + quad * 8;
      float4 a = *(const float4*)(qnctx + off);
      float4 b = *(const float4*)(qnctx + off + 4);
      float xs[8] = {a.x, a.y, a.z, a.w, b.x, b.y, b.z, b.w};
#pragma unroll
      for (int j = 0; j < 8; ++j) {
        unsigned short hi, lo;
        bsplit(xs[j] * 0.125f, hi, lo);   // fold 1/sqrt(64), exact
        qAh[kk][j] = (short)hi; qAl[kk][j] = (short)lo;
      }
      float4 c = *(const float4*)(Qr + off);
      float4 d = *(const float4*)(Qr + off + 4);
      float ys[8] = {c.x, c.y, c.z, c.w, d.x, d.y, d.z, d.w};
#pragma unroll
      for (int j = 0; j < 8; ++j) {
        unsigned short hi, lo;
        bsplit(ys[j] * 0.125f, hi, lo);
        qBh[kk][j] = (short)hi; qBl[kk][j] = (short)lo;
      }
    }
  }

  floatx4 acco[4];
  float m_[4], l_[4];
#pragma unroll
  for (int nt = 0; nt < 4; ++nt) acco[nt] = (floatx4){0.f, 0.f, 0.f, 0.f};
#pragma unroll
  for (int r = 0; r < 4; ++r) { m_[r] = -3.0e38f; l_[r] = 0.f; }

  const int ntiles = 32 + (q0 >> 6) + 1;

  short8 kh[2][4], kl[2][4];   // K fragments (hi/lo), current tile
  short8 vh[2][4], vl[2][4];   // V^T fragments (hi/lo), current tile

  auto loadK = [&](int kt2) {
    const unsigned short *ph, *pl;
    if (kt2 < 32) { const size_t tk = (size_t)(h * 32 + kt2);
                    ph = kbkS + tk * 8192; pl = ph + 4096; }
    else          { const size_t tk = (size_t)(hkv * 16 + (kt2 - 32));
                    ph = KPhi + tk * 4096; pl = ph + 524288; }
#pragma unroll
    for (int kk = 0; kk < 2; ++kk)
#pragma unroll
      for (int nt = 0; nt < 4; ++nt) {
        kh[kk][nt] = *(const short8*)(ph + (kk * 4 + nt) * 512 + fl);
        kl[kk][nt] = *(const short8*)(pl + (kk * 4 + nt) * 512 + fl);
      }
  };
  auto loadV = [&](int kt2) {
    const unsigned short *ph, *pl;
    if (kt2 < 32) { const size_t tk = (size_t)(h * 32 + kt2);
                    ph = vtKBhi + tk * 4096; pl = ph + 4194304; }
    else          { const size_t tk = (size_t)(hkv * 16 + (kt2 - 32));
                    ph = vtPhi + tk * 4096; pl = ph + 524288; }
#pragma unroll
    for (int kk = 0; kk < 2; ++kk)
#pragma unroll
      for (int nt = 0; nt < 4; ++nt) {
        vh[kk][nt] = *(const short8*)(ph + (kk * 4 + nt) * 512 + fl);
        vl[kk][nt] = *(const short8*)(pl + (kk * 4 + nt) * 512 + fl);
      }
  };

  loadK(0);   // prologue

  for (int kt = 0; kt < ntiles; ++kt) {
    const bool isKB = kt < 32;
    loadV(kt);                          // in flight during QK+softmax
    __builtin_amdgcn_s_barrier();       // convergence only (no shared staging)

    floatx4 accs[4];
#pragma unroll
    for (int nt = 0; nt < 4; ++nt) accs[nt] = (floatx4){0.f, 0.f, 0.f, 0.f};
    __builtin_amdgcn_s_setprio(1);
    if (isKB) {
#pragma unroll
      for (int kk = 0; kk < 2; ++kk)
#pragma unroll
        for (int nt = 0; nt < 4; ++nt) {
          accs[nt] = __builtin_amdgcn_mfma_f32_16x16x32_bf16(qAh[kk], kh[kk][nt], accs[nt], 0, 0, 0);
          accs[nt] = __builtin_amdgcn_mfma_f32_16x16x32_bf16(qAl[kk], kh[kk][nt], accs[nt], 0, 0, 0);
          accs[nt] = __builtin_amdgcn_mfma_f32_16x16x32_bf16(qAh[kk], kl[kk][nt], accs[nt], 0, 0, 0);
        }
    } else {
#pragma unroll
      for (int kk = 0; kk < 2; ++kk)
#pragma unroll
        for (int nt = 0; nt < 4; ++nt) {
          accs[nt] = __builtin_amdgcn_mfma_f32_16x16x32_bf16(qBh[kk], kh[kk][nt], accs[nt], 0, 0, 0);
          accs[nt] = __builtin_amdgcn_mfma_f32_16x16x32_bf16(qBl[kk], kh[kk][nt], accs[nt], 0, 0, 0);
          accs[nt] = __builtin_amdgcn_mfma_f32_16x16x32_bf16(qBh[kk], kl[kk][nt], accs[nt], 0, 0, 0);
        }
    }
    __builtin_amdgcn_s_setprio(0);

    // Bias/mask: KB tiles = uniform bias; prompt non-diagonal = none; only the
    // final (diagonal) tile needs the causal mask.
    float sv[4][4];
    if (isKB) {
#pragma unroll
      for (int nt = 0; nt < 4; ++nt)
#pragma unroll
        for (int r = 0; r < 4; ++r) sv[nt][r] = accs[nt][r] + kbbias;
    } else if (kt < ntiles - 1) {
#pragma unroll
      for (int nt = 0; nt < 4; ++nt)
#pragma unroll
        for (int r = 0; r < 4; ++r) sv[nt][r] = accs[nt][r];
    } else {
#pragma unroll
      for (int nt = 0; nt < 4; ++nt) {
        int kl_ = nt * 16 + col;
#pragma unroll
        for (int r = 0; r < 4; ++r) {
          int ql_ = w * 16 + quad * 4 + r;
          sv[nt][r] = accs[nt][r] + ((kl_ <= ql_) ? 0.0f : -1e9f);
        }
      }
    }
#pragma unroll
    for (int r = 0; r < 4; ++r) {
      float rmax = fmaxf(fmaxf(sv[0][r], sv[1][r]), fmaxf(sv[2][r], sv[3][r]));
#pragma unroll
      for (int off = 8; off; off >>= 1) rmax = fmaxf(rmax, __shfl_xor(rmax, off));
      float mnew = fmaxf(m_[r], rmax);
      float alpha = __expf(m_[r] - mnew);
      float psum = 0.f;
#pragma unroll
      for (int nt = 0; nt < 4; ++nt) {
        float p = __expf(sv[nt][r] - mnew);
        sv[nt][r] = p;
        psum += p;
      }
#pragma unroll
      for (int off = 8; off; off >>= 1) psum += __shfl_xor(psum, off);
      l_[r] = l_[r] * alpha + psum;
      m_[r] = mnew;
#pragma unroll
      for (int nt = 0; nt < 4; ++nt) acco[nt][r] *= alpha;
    }

    // Prefetch next tile's K (WAR on kh/kl keeps these after the QK MFMAs;
    // in flight during P-pack + PV). Clamped redundant load on last tile.
    loadK(kt + 1 < ntiles ? kt + 1 : kt);

    // P truncation split -> packed hi|lo<<16 (err <= 2^-16 * p; p in [0,1]).
#pragma unroll
    for (int nt = 0; nt < 4; ++nt)
#pragma unroll
      for (int r = 0; r < 4; ++r) {
        unsigned xb = __float_as_uint(sv[nt][r]);
        float hf = __uint_as_float(xb & 0xffff0000u);
        unsigned db = __float_as_uint(sv[nt][r] - hf);
        Pw[(quad * 4 + r) * 68 + nt * 16 + col] = (xb >> 16) | (db & 0xffff0000u);
      }

#pragma unroll
    for (int kk = 0; kk < 2; ++kk) {
      uint4 pa = *(const uint4*)&Pw[col * 68 + kk * 32 + quad * 8];
      uint4 pb = *(const uint4*)&Pw[col * 68 + kk * 32 + quad * 8 + 4];
      union { unsigned int u[4]; short8 s; } uh, ul;
      uh.u[0] = (pa.x & 0xffffu) | (pa.y << 16);
      uh.u[1] = (pa.z & 0xffffu) | (pa.w << 16);
      uh.u[2] = (pb.x & 0xffffu) | (pb.y << 16);
      uh.u[3] = (pb.z & 0xffffu) | (pb.w << 16);
      ul.u[0] = (pa.x >> 16) | (pa.y & 0xffff0000u);
      ul.u[1] = (pa.z >> 16) | (pa.w & 0xffff0000u);
      ul.u[2] = (pb.x >> 16) | (pb.y & 0xffff0000u);
      ul.u[3] = (pb.z >> 16) | (pb.w & 0xffff0000u);
      short8 ph8 = uh.s, pl8 = ul.s;
      __builtin_amdgcn_s_setprio(1);
#pragma unroll
      for (int nt = 0; nt < 4; ++nt) {
        acco[nt] = __builtin_amdgcn_mfma_f32_16x16x32_bf16(ph8, vh[kk][nt], acco[nt], 0, 0, 0);
        acco[nt] = __builtin_amdgcn_mfma_f32_16x16x32_bf16(pl8, vh[kk][nt], acco[nt], 0, 0, 0);
        acco[nt] = __builtin_amdgcn_mfma_f32_16x16x32_bf16(ph8, vl[kk][nt], acco[nt], 0, 0, 0);
      }
      __builtin_amdgcn_s_setprio(0);
    }
  }

#pragma unroll
  for (int r = 0; r < 4; ++r) {
    float linv = 1.0f / l_[r];
#pragma unroll
    for (int nt = 0; nt < 4; ++nt)
      qnctx[(size_t)(q0 + w * 16 + quad * 4 + r) * 2048 + h * 64 + nt * 16 + col] =
          acco[nt][r] * linv;
  }
}

// ---------------------------------------------------------------------------
extern "C" void kernel_launch(void* const* d_in, const int* in_sizes, int n_in,
                              void* d_out, int out_size, void* d_ws, size_t ws_size,
                              hipStream_t stream) {
  (void)in_sizes; (void)n_in; (void)out_size; (void)ws_size;
  const float* hidden = (const float*)d_in[0];
  float* kbk = (float*)d_in[2];              // tile-split in place (restored each launch)
  const float* kbv = (const float*)d_in[3];
  const float* Wq  = (const float*)d_in[4];
  const float* Wk  = (const float*)d_in[5];
  const float* Wv  = (const float*)d_in[6];
  const float* Wo  = (const float*)d_in[7];
  const float* Wqn = (const float*)d_in[8];
  const int*   pos = (const int*)d_in[9];

  char* ws = (char*)d_ws;
  double* sums = (double*)(ws + WS_SUMS);
  float* dq1 = (float*)(ws + WS_DQ1);
  float* dq2 = (float*)(ws + WS_DQ2);
  unsigned short* xq   = (unsigned short*)(ws + WS_XQ);
  unsigned short* wall = (unsigned short*)(ws + WS_WALL);
  unsigned short* vtKBhi = (unsigned short*)(ws + WS_WALL);              // after GEMM
  unsigned short* vtPhi  = (unsigned short*)(ws + WS_WALL + 16777216);   // after GEMM
  unsigned short* wqo  = (unsigned short*)(ws + WS_QB);                  // after attn
  float* Qb  = (float*)(ws + WS_QB);
  unsigned short* KPhi = (unsigned short*)(ws + WS_KB);                  // prompt K hi
  unsigned short* KPlo = KPhi + 524288;                                  // prompt K lo
  float* Vb  = (float*)(ws + WS_VB);
  float* QNC = (float*)(ws + WS_QN);   // kb_q, then CTX
  float2* ropetab = (float2*)(ws + WS_ROPET);

  hipMemsetAsync(sums, 0, 64, stream);

  k_ropetab<<<128, 256, 0, stream>>>(pos, ropetab);
  k_abssum5<<<dim3(128, 5), 256, 0, stream>>>(Wq, Wk, Wv, Wo, Wqn, sums);
  k_wquant4<<<10240, 256, 0, stream>>>(Wq, Wk, Wv, Wqn, wall, sums);
  k_aquant<<<cQ, 256, 0, stream>>>(hidden, xq, dq1, cH);

  // Fused Q/K/V/QN GEMM with RoPE epilogue: 64x64 tiles, grid 80x16 = 1280
  // blocks = exactly 5/CU (balanced; old 320-block grid left a 64-block
  // straggler round with 75% of the GPU idle).
  k_gemm64u<<<dim3(80, 16), 256, 0, stream>>>(xq, wall, dq1, sums, ropetab,
                                              Qb, KPhi, KPlo, Vb, QNC, 0);

  // V transposes (1152 blocks) + kbk in-place tile split (1024 blocks)
  k_prep<<<1152 + 1024, 256, 0, stream>>>(kbv, Vb, vtKBhi, vtPhi, kbk);

  k_attn_mfma<<<dim3(cNH, cQ / 64), 256, 0, stream>>>(
      Qb, QNC, KPhi, (const unsigned short*)kbk, vtKBhi, vtPhi);

  k_wquant<<<4096, 256, 0, stream>>>(Wo, wqo, sums + 3, INV_BIG);
  k_aquant<<<cQ, 256, 0, stream>>>(QNC, xq, dq2, cH);

  // O projection: 64x64 tiles, grid 32x16 = 512 blocks (2/CU)
  k_gemm64u<<<dim3(32, 16), 256, 0, stream>>>(xq, wqo, dq2, sums, ropetab,
                                              (float*)d_out, nullptr, nullptr,
                                              nullptr, nullptr, 1);
}

// Round 11
// 364.587 us; speedup vs baseline: 1.1451x; 1.0445x over previous
//
#include <hip/hip_runtime.h>
#include <hip/hip_bf16.h>
#include <stdint.h>
#include <math.h>

// Problem constants (B=1)
#define cH    2048
#define cQ    1024
#define cNH   32
#define cNKV  8
#define cKB   2048

#define INV_BIG   (1.0f/4194304.0f)   // 1/(2048*2048)
#define INV_SMALL (1.0f/1048576.0f)   // 1/(512*2048)

// ---------------------------------------------------------------------------
// Workspace layout (bytes). Total = 46,407,936 (<= proven 48,242,944).
#define WS_SUMS 0           // 8 doubles (5 used)
#define WS_DQ1  256         // 1024 f32
#define WS_DQ2  4352        // 1024 f32
#define WS_XQ   8448        // 1024x2048 bf16 (xq1; reused as xq2 after attention)
#define WS_WALL 4202752     // 5120x2048 bf16 weights; DEAD after fused GEMM ->
                            //   vtKBhi 8MB frag-tiles [h*32+kt], vtKBlo at +8MB,
                            //   vtPhi 1MB frag-tiles [hkv*16+kt] at +16MB, vtPlo +17MB
#define WS_QB   25174272    // 1024x2048 f32 rotated q; reused as wqo after attn
#define WS_KB   33562880    // prompt K planes: KPhi 1MB frag-tiles, KPlo +1MB
#define WS_VB   35660032    // 1024x512 f32 v (source for vtrans)
#define WS_QN   37757184    // 1024x2048 f32 kb_q; reused as CTX (same rows+cols per block)
#define WS_ROPET 46145792   // 1024x32 float2 cos/sin table (262,144 B)

// Fragment-ordered 8KB tile plane: fragment f = kk*4 + nt (kk = inner-dim>>5,
// nt = outer-dim>>4); within fragment, lane = (outer&15) + 16*((inner&31)>>3),
// elem j = inner&7. One fragment = 64 lanes x 16B = 1KB, loads coalesced.

using short8  = __attribute__((ext_vector_type(8))) short;
using floatx4 = __attribute__((ext_vector_type(4))) float;

__device__ __forceinline__ void bsplit(float x, unsigned short& hi, unsigned short& lo) {
  __hip_bfloat16 h = __float2bfloat16(x);          // RN
  float hf = __bfloat162float(h);
  __hip_bfloat16 l = __float2bfloat16(x - hf);     // exact residual, RN again
  hi = *(unsigned short*)&h;
  lo = *(unsigned short*)&l;
}

__device__ __forceinline__ unsigned short tern(float v, float ws) {
  float q = rintf(v * ws);
  q = fminf(fmaxf(q, -1.0f), 1.0f);
  return (unsigned short)(__float_as_uint(q) >> 16);
}

// Async 16B global->LDS (direct-to-shared DMA; dest = wave-uniform base + lane*16).
__device__ __forceinline__ void gload16(const void* g, void* l) {
  __builtin_amdgcn_global_load_lds((const __attribute__((address_space(1))) void*)g,
                                   (__attribute__((address_space(3))) void*)l, 16, 0, 0);
}

// ---------------------------------------------------------------------------
// Fused pre-pass: blocks [0,128) = RoPE cos/sin table (fp64 math once);
// blocks [128,768) = 5-segment weight |.| sums (128 blocks per segment).
__global__ void k_pre(const int* __restrict__ pos, float2* __restrict__ tab,
                      const float* __restrict__ w0, const float* __restrict__ w1,
                      const float* __restrict__ w2, const float* __restrict__ w3,
                      const float* __restrict__ w4, double* __restrict__ out) {
  __shared__ double red[256];
  const int b = blockIdx.x;
  if (b < 128) {
    int i = b * 256 + threadIdx.x;   // 32768
    int t = i >> 5, d = i & 31;
    double p = (double)pos[t];
    double ang = p * pow(10000.0, -(double)d / 32.0);
    tab[i] = make_float2((float)cos(ang), (float)sin(ang));
    return;
  }
  const int bb = b - 128;
  const int seg = bb >> 7;          // 0..4
  const int bx = bb & 127;
  const float* w = seg == 0 ? w0 : seg == 1 ? w1 : seg == 2 ? w2 : seg == 3 ? w3 : w4;
  const int n4 = ((seg == 1 || seg == 2) ? 512 * 2048 : 2048 * 2048) / 4;
  double s = 0.0;
  for (int i = bx * 256 + threadIdx.x; i < n4; i += 128 * 256) {
    float4 x = *(const float4*)(w + (size_t)i * 4);
    s += (double)fabsf(x.x) + (double)fabsf(x.y) + (double)fabsf(x.z) + (double)fabsf(x.w);
  }
  red[threadIdx.x] = s;
  __syncthreads();
  for (int o = 128; o > 0; o >>= 1) {
    if ((int)threadIdx.x < o) red[threadIdx.x] += red[threadIdx.x + o];
    __syncthreads();
  }
  if (threadIdx.x == 0) atomicAdd(out + seg, red[0]);
}

// ---------------------------------------------------------------------------
// Fused quant pass 1: blocks [0,10240) = ternary quant of Wq/Wk/Wv/Wqn
// (4 elems/thread); blocks [10240,11264) = per-token int8 absmax activation
// quant of hidden -> bf16-int xq (independent of sums).
__global__ void k_quant1(const float* __restrict__ Wq, const float* __restrict__ Wk,
                         const float* __restrict__ Wv, const float* __restrict__ Wqn,
                         unsigned short* __restrict__ wall, const double* __restrict__ sums,
                         const float* __restrict__ hidden, unsigned short* __restrict__ xq,
                         float* __restrict__ dq) {
  __shared__ float red[256];
  const int b = blockIdx.x;
  if (b < 10240) {
    size_t i = ((size_t)b * 256 + threadIdx.x) * 4;   // 0 .. 10485756
    const float* src; size_t off; double s; float inv;
    if (i < 4194304)      { src = Wq;  off = 0;       s = sums[0]; inv = INV_BIG; }
    else if (i < 5242880) { src = Wk;  off = 4194304; s = sums[1]; inv = INV_SMALL; }
    else if (i < 6291456) { src = Wv;  off = 5242880; s = sums[2]; inv = INV_SMALL; }
    else                  { src = Wqn; off = 6291456; s = sums[4]; inv = INV_BIG; }
    float ws = 1.0f / fmaxf((float)s * inv, 1e-5f);
    float4 x = *(const float4*)(src + (i - off));
    ushort4 o;
    o.x = tern(x.x, ws); o.y = tern(x.y, ws); o.z = tern(x.z, ws); o.w = tern(x.w, ws);
    *(ushort4*)(wall + i) = o;
    return;
  }
  const int t = b - 10240;
  const float4* xr = (const float4*)(hidden + (size_t)t * cH);
  float m = 0.0f;
  for (int i = threadIdx.x; i < 512; i += 256) {
    float4 v = xr[i];
    m = fmaxf(m, fmaxf(fmaxf(fabsf(v.x), fabsf(v.y)), fmaxf(fabsf(v.z), fabsf(v.w))));
  }
  red[threadIdx.x] = m;
  __syncthreads();
  for (int o = 128; o > 0; o >>= 1) {
    if ((int)threadIdx.x < o) red[threadIdx.x] = fmaxf(red[threadIdx.x], red[threadIdx.x + o]);
    __syncthreads();
  }
  float amax = fmaxf(red[0], 1e-5f);
  float as = 127.0f / amax;
  ushort4* xo = (ushort4*)(xq + (size_t)t * cH);
  for (int i = threadIdx.x; i < 512; i += 256) {
    float4 v = xr[i];
    ushort4 o;
    float q;
    q = fminf(fmaxf(rintf(v.x * as), -128.0f), 127.0f); o.x = (unsigned short)(__float_as_uint(q) >> 16);
    q = fminf(fmaxf(rintf(v.y * as), -128.0f), 127.0f); o.y = (unsigned short)(__float_as_uint(q) >> 16);
    q = fminf(fmaxf(rintf(v.z * as), -128.0f), 127.0f); o.z = (unsigned short)(__float_as_uint(q) >> 16);
    q = fminf(fmaxf(rintf(v.w * as), -128.0f), 127.0f); o.w = (unsigned short)(__float_as_uint(q) >> 16);
    xo[i] = o;
  }
  if (threadIdx.x == 0) dq[t] = amax / 127.0f;
}

// ---------------------------------------------------------------------------
// Fused quant pass 2 (post-attention): blocks [0,4096) = ternary quant of Wo
// -> wqo (overlays Qb, dead after attn); blocks [4096,5120) = activation
// quant of CTX -> xq (xq dead after QKV GEMM).
__global__ void k_quant2(const float* __restrict__ Wo, unsigned short* __restrict__ wqo,
                         const double* __restrict__ sums,
                         const float* __restrict__ ctx, unsigned short* __restrict__ xq,
                         float* __restrict__ dq) {
  __shared__ float red[256];
  const int b = blockIdx.x;
  if (b < 4096) {
    size_t i = ((size_t)b * 256 + threadIdx.x) * 4;
    float ws = 1.0f / fmaxf((float)sums[3] * INV_BIG, 1e-5f);
    float4 x = *(const float4*)(Wo + i);
    ushort4 o;
    o.x = tern(x.x, ws); o.y = tern(x.y, ws); o.z = tern(x.z, ws); o.w = tern(x.w, ws);
    *(ushort4*)(wqo + i) = o;
    return;
  }
  const int t = b - 4096;
  const float4* xr = (const float4*)(ctx + (size_t)t * cH);
  float m = 0.0f;
  for (int i = threadIdx.x; i < 512; i += 256) {
    float4 v = xr[i];
    m = fmaxf(m, fmaxf(fmaxf(fabsf(v.x), fabsf(v.y)), fmaxf(fabsf(v.z), fabsf(v.w))));
  }
  red[threadIdx.x] = m;
  __syncthreads();
  for (int o = 128; o > 0; o >>= 1) {
    if ((int)threadIdx.x < o) red[threadIdx.x] = fmaxf(red[threadIdx.x], red[threadIdx.x + o]);
    __syncthreads();
  }
  float amax = fmaxf(red[0], 1e-5f);
  float as = 127.0f / amax;
  ushort4* xo = (ushort4*)(xq + (size_t)t * cH);
  for (int i = threadIdx.x; i < 512; i += 256) {
    float4 v = xr[i];
    ushort4 o;
    float q;
    q = fminf(fmaxf(rintf(v.x * as), -128.0f), 127.0f); o.x = (unsigned short)(__float_as_uint(q) >> 16);
    q = fminf(fmaxf(rintf(v.y * as), -128.0f), 127.0f); o.y = (unsigned short)(__float_as_uint(q) >> 16);
    q = fminf(fmaxf(rintf(v.z * as), -128.0f), 127.0f); o.z = (unsigned short)(__float_as_uint(q) >> 16);
    q = fminf(fmaxf(rintf(v.w * as), -128.0f), 127.0f); o.w = (unsigned short)(__float_as_uint(q) >> 16);
    xo[i] = o;
  }
  if (threadIdx.x == 0) dq[t] = amax / 127.0f;
}

// ---------------------------------------------------------------------------
// Unified bf16-MFMA BitLinear GEMM, 64x64 tiles, 4 waves x (16 M-rows, full
// 64 N-cols) each — keeps the RoPE pair (d, d+32) in-thread (acc[h]/acc[h+2]).
// QKV grid 80x16 = 1280 blocks = exactly 5/CU. LDS 32KB x 5 blocks = 160KB
// exact fit. DMA staging + counted-vmcnt double buffer (r7).
// mode 0: fused QKV+QN with RoPE/K-split epilogue; mode 1: O-projection.
__global__ __launch_bounds__(256) void k_gemm64u(
    const unsigned short* __restrict__ Aq, const unsigned short* __restrict__ Ball,
    const float* __restrict__ adq, const double* __restrict__ sums,
    const float2* __restrict__ ropetab,
    float* __restrict__ oQ, unsigned short* __restrict__ oKhi,
    unsigned short* __restrict__ oKlo,
    float* __restrict__ oV, float* __restrict__ oQN, int mode) {
  __shared__ __attribute__((aligned(16))) unsigned short As[2][64 * 64];
  __shared__ __attribute__((aligned(16))) unsigned short Bs[2][64 * 64];
  const int t = threadIdx.x;
  const int lane = t & 63;
  const int row16 = lane & 15, q = lane >> 4;
  const int w = t >> 6;
  const int bx = blockIdx.x;
  const int m0 = blockIdx.y * 64;
  const unsigned short* Bp = Ball + (size_t)bx * 64 * 2048;
  const int swr = row16 & 7;                 // fragment-read XOR key

  floatx4 acc[4];
#pragma unroll
  for (int h = 0; h < 4; ++h) acc[h] = (floatx4){0.f, 0.f, 0.f, 0.f};

  auto stageAB = [&](int k0s, int b) {
#pragma unroll
    for (int i = 0; i < 2; ++i) {
      int c = t + 256 * i;
      int row = c >> 3, g8 = c & 7;
      int sa = (g8 ^ (row & 7)) * 8;         // source col slot swizzle
      gload16(Aq + (size_t)(m0 + row) * 2048 + k0s + sa, &As[b][w * 512 + i * 2048]);
      gload16(Bp + (size_t)row * 2048 + k0s + sa, &Bs[b][w * 512 + i * 2048]);
    }
  };

  stageAB(0, 0);   // prologue: 4 DMA outstanding
  for (int k0 = 0; k0 < 2048; k0 += 64) {
    const int cur = (k0 >> 6) & 1;
    const int kn = (k0 + 64 < 2048) ? k0 + 64 : k0;   // clamped redundant last
    stageAB(kn, cur ^ 1);                             // +4 -> 8 outstanding
    asm volatile("s_waitcnt vmcnt(4)" ::: "memory");  // wait current tile's 4
    __builtin_amdgcn_s_barrier();
#pragma unroll
    for (int kk = 0; kk < 2; ++kk) {
      short8 af, bf[4];
      const int sw = ((kk * 4 + q) ^ swr) << 3;
      af = *(const short8*)&As[cur][(w * 16 + row16) * 64 + sw];
#pragma unroll
      for (int h = 0; h < 4; ++h)
        bf[h] = *(const short8*)&Bs[cur][(h * 16 + row16) * 64 + sw];
#pragma unroll
      for (int h = 0; h < 4; ++h)
        acc[h] = __builtin_amdgcn_mfma_f32_16x16x32_bf16(af, bf[h], acc[h], 0, 0, 0);
    }
    __builtin_amdgcn_s_barrier();   // reads of buf[cur] done before it is re-staged
  }
  asm volatile("s_waitcnt vmcnt(0)" ::: "memory");   // drain redundant last prefetch

  // Segment decode. QKV (mode 0): bx<32 Q | 32..39 K | 40..47 V | 48..79 QN.
  float* outp = nullptr; int Nout = 0, nb0; float wdq;
  if (mode == 1)      { outp = oQ;  Nout = 2048; nb0 = bx * 64;        wdq = fmaxf((float)sums[3] * INV_BIG,   1e-5f); }
  else if (bx < 32)   { outp = oQ;  Nout = 2048; nb0 = bx * 64;        wdq = fmaxf((float)sums[0] * INV_BIG,   1e-5f); }
  else if (bx < 40)   {             Nout = 512;  nb0 = (bx - 32) * 64; wdq = fmaxf((float)sums[1] * INV_SMALL, 1e-5f); }
  else if (bx < 48)   { outp = oV;  Nout = 512;  nb0 = (bx - 40) * 64; wdq = fmaxf((float)sums[2] * INV_SMALL, 1e-5f); }
  else                { outp = oQN; Nout = 2048; nb0 = (bx - 48) * 64; wdq = fmaxf((float)sums[4] * INV_BIG,   1e-5f); }

  if (mode == 0 && bx < 40) {
    // RoPE epilogue. nb0 is 64-aligned -> head-relative d = h*16 + row16;
    // pairs (d, d+32) = (acc[0],acc[2]) and (acc[1],acc[3]) in-thread.
#pragma unroll
    for (int r = 0; r < 4; ++r) {
      int m = m0 + w * 16 + q * 4 + r;
      float s = adq[m] * wdq;
      float2 cs0 = ropetab[m * 32 + row16];        // d = row16
      float2 cs1 = ropetab[m * 32 + 16 + row16];   // d = 16 + row16
      float v0 = acc[0][r] * s, v1 = acc[1][r] * s;
      float v2 = acc[2][r] * s, v3 = acc[3][r] * s;
      float o0 = v0 * cs0.x - v2 * cs0.y;
      float o2 = v2 * cs0.x + v0 * cs0.y;
      float o1 = v1 * cs1.x - v3 * cs1.y;
      float o3 = v3 * cs1.x + v1 * cs1.y;
      if (bx < 32) {   // Q: fp32
        size_t base = (size_t)m * 2048 + nb0;
        outp[base + row16]      = o0;
        outp[base + 16 + row16] = o1;
        outp[base + 32 + row16] = o2;
        outp[base + 48 + row16] = o3;
      } else {
        // K: RN-bsplit into fragment-ordered hi/lo planes.
        // value o_h: key rr = m&63 (tile kt_ = m>>6), d = h*16 + row16.
        int hkv_ = bx - 32;
        int kt_ = m >> 6, rr = m & 63;
        size_t tb = ((size_t)(hkv_ * 16 + kt_)) * 4096;
        int lbase = (rr & 15) + ((row16 >> 3) << 4);
        int ntb = (rr >> 4) * 512 + (row16 & 7);
        unsigned short hi, lo; int ix;
        bsplit(o0, hi, lo); ix = ntb + (lbase     ) * 8;          oKhi[tb + ix] = hi; oKlo[tb + ix] = lo;
        bsplit(o1, hi, lo); ix = ntb + (lbase + 32) * 8;          oKhi[tb + ix] = hi; oKlo[tb + ix] = lo;
        bsplit(o2, hi, lo); ix = ntb + (lbase     ) * 8 + 2048;   oKhi[tb + ix] = hi; oKlo[tb + ix] = lo;
        bsplit(o3, hi, lo); ix = ntb + (lbase + 32) * 8 + 2048;   oKhi[tb + ix] = hi; oKlo[tb + ix] = lo;
      }
    }
  } else {
#pragma unroll
    for (int r = 0; r < 4; ++r) {
      int m = m0 + w * 16 + q * 4 + r;
      float s = adq[m] * wdq;
#pragma unroll
      for (int h = 0; h < 4; ++h)
        outp[(size_t)m * Nout + nb0 + h * 16 + row16] = acc[h][r] * s;
    }
  }
}

// ---------------------------------------------------------------------------
// Merged prep. All outputs are 8KB fragment-ordered ushort tile planes (see
// header comment) so attention loads fragments global->VGPR fully coalesced.
//   blocks [0,1024):    vtKB  (transpose kbv -> V^T, RN-bsplit hi/lo planes)
//   blocks [1024,1152): vtP   (transpose Vb  -> V^T, RN-bsplit hi/lo planes)
//   blocks >= 1152:     kbk   in-place tile split [key][d] -> [hi 8KB | lo 8KB]
__global__ __launch_bounds__(256) void k_prep(
    const float* __restrict__ kbv, const float* __restrict__ Vb,
    unsigned short* __restrict__ vtKBhi, unsigned short* __restrict__ vtPhi,
    float* __restrict__ kbk) {
  const int b = blockIdx.x;
  const int t = threadIdx.x;
  if (b >= 1152) {
    float* tile = kbk + (size_t)(b - 1152) * 4096;   // 64x64 f32 [key][d], contiguous
    float v[2][8];
#pragma unroll
    for (int u = 0; u < 2; ++u) {
      int task = t + 256 * u;            // 512 tasks: key r = task>>3, d-slot s = task&7
      int r = task >> 3, s = task & 7;
      *(float4*)&v[u][0] = *(const float4*)(tile + r * 64 + s * 8);
      *(float4*)&v[u][4] = *(const float4*)(tile + r * 64 + s * 8 + 4);
    }
    __syncthreads();                     // all reads before any in-place write
    unsigned short* up = (unsigned short*)tile;
#pragma unroll
    for (int u = 0; u < 2; ++u) {
      int task = t + 256 * u;
      int r = task >> 3, s = task & 7;   // element (key=r, d=s*8+j)
      union { unsigned short u16[8]; uint4 q; } hi, lo;
#pragma unroll
      for (int j = 0; j < 8; ++j) bsplit(v[u][j], hi.u16[j], lo.u16[j]);
      // K-frag: frag = (d>>5)*4 + (key>>4); lane = (key&15) + 16*((d&31)>>3); j = d&7
      size_t off = (size_t)(((s >> 2) * 4 + (r >> 4)) * 512 + ((r & 15) + ((s & 3) << 4)) * 8);
      *(uint4*)(up + off)        = hi.q;
      *(uint4*)(up + 4096 + off) = lo.q;
    }
    return;
  }
  __shared__ float Lf[64 * 65];
  const float* src; unsigned short *dhi, *dlo; int srcStride;
  if (b < 1024) {
    int h = b >> 5, kt = b & 31;
    src = kbv + ((size_t)h * cKB + kt * 64) * 64; srcStride = 64;
    dhi = vtKBhi + (size_t)b * 4096; dlo = dhi + 4194304;
  } else {
    int bb = b - 1024;
    int hkv = bb >> 4, kt = bb & 15;
    src = Vb + (size_t)(kt * 64) * 512 + hkv * 64; srcStride = 512;
    dhi = vtPhi + (size_t)bb * 4096; dlo = dhi + 524288;
  }
#pragma unroll
  for (int i = 0; i < 4; ++i) {
    int c = t + 256 * i;
    int row = c >> 4, c4 = (c & 15) * 4;       // row = key, col = d
    float4 x = *(const float4*)(src + (size_t)row * srcStride + c4);
    Lf[row * 65 + c4 + 0] = x.x;
    Lf[row * 65 + c4 + 1] = x.y;
    Lf[row * 65 + c4 + 2] = x.z;
    Lf[row * 65 + c4 + 3] = x.w;
  }
  __syncthreads();
#pragma unroll
  for (int u = 0; u < 2; ++u) {
    int task = t + 256 * u;                    // d = task>>3, key slot s = task&7
    int d = task >> 3, s = task & 7;           // element (d, key=s*8+j)
    union { unsigned short u16[8]; uint4 q; } hi, lo;
#pragma unroll
    for (int j = 0; j < 8; ++j) bsplit(Lf[(s * 8 + j) * 65 + d], hi.u16[j], lo.u16[j]);
    // V^T-frag: frag = (key>>5)*4 + (d>>4); lane = (d&15) + 16*((key&31)>>3); j = key&7
    size_t off = (size_t)(((s >> 2) * 4 + (d >> 4)) * 512 + ((d & 15) + ((s & 3) << 4)) * 8);
    *(uint4*)(dhi + off) = hi.q;
    *(uint4*)(dlo + off) = lo.q;
  }
}

// ---------------------------------------------------------------------------
// Split-bf16 MFMA flash attention, REGISTER-DIRECT K/V — exact r7 structure
// (the measured equilibrium: 512 blocks, 2/CU, 2 waves/SIMD; all structural
// variants tried — LDS-DMA, dbuf-vmcnt, KV-split 4/CU, fat-wave 1/SIMD,
// d-split PV, setprio — land at >= this).
__global__ __launch_bounds__(256, 2) void k_attn_mfma(
    const float* __restrict__ Qr, float* qnctx,
    const unsigned short* __restrict__ KPhi,    // prompt K planes, lo at +524288
    const unsigned short* __restrict__ kbkS,    // KB K tiles [h*32+kt][hi 4096 | lo 4096]
    const unsigned short* __restrict__ vtKBhi,  // KB V^T planes, lo at +4194304
    const unsigned short* __restrict__ vtPhi) { // prompt V^T planes, lo at +524288
  __shared__ __attribute__((aligned(16))) unsigned int Pbuf[4][16 * 68];   // per-wave

  const int t = threadIdx.x;
  const int lane = t & 63;
  const int col = lane & 15;
  const int quad = lane >> 4;
  const int w = t >> 6;
  const int h = blockIdx.x;
  const int q0 = blockIdx.y * 64;
  const int hkv = h >> 2;
  const float kbbias = 0.69314718055994531f;   // log(4096)-log(2048)
  unsigned int* Pw = &Pbuf[w][0];
  const int fl = lane * 8;                     // fragment lane offset (ushorts)

  short8 qAh[2], qAl[2];   // kb_q (not rotated)
  short8 qBh[2], qBl[2];   // rotated prompt q
  {
#pragma unroll
    for (int kk = 0; kk < 2; ++kk) {
      const size_t off = (size_t)(q0 + w * 16 + col) * 2048 + h * 64 + kk * 32 + quad * 8;
      float4 a = *(const float4*)(qnctx + off);
      float4 b = *(const float4*)(qnctx + off + 4);
      float xs[8] = {a.x, a.y, a.z, a.w, b.x, b.y, b.z, b.w};
#pragma unroll
      for (int j = 0; j < 8; ++j) {
        unsigned short hi, lo;
        bsplit(xs[j] * 0.125f, hi, lo);   // fold 1/sqrt(64), exact
        qAh[kk][j] = (short)hi; qAl[kk][j] = (short)lo;
      }
      float4 c = *(const float4*)(Qr + off);
      float4 d = *(const float4*)(Qr + off + 4);
      float ys[8] = {c.x, c.y, c.z, c.w, d.x, d.y, d.z, d.w};
#pragma unroll
      for (int j = 0; j < 8; ++j) {
        unsigned short hi, lo;
        bsplit(ys[j] * 0.125f, hi, lo);
        qBh[kk][j] = (short)hi; qBl[kk][j] = (short)lo;
      }
    }
  }

  floatx4 acco[4];
  float m_[4], l_[4];
#pragma unroll
  for (int nt = 0; nt < 4; ++nt) acco[nt] = (floatx4){0.f, 0.f, 0.f, 0.f};
#pragma unroll
  for (int r = 0; r < 4; ++r) { m_[r] = -3.0e38f; l_[r] = 0.f; }

  const int ntiles = 32 + (q0 >> 6) + 1;

  short8 kh[2][4], kl[2][4];   // K fragments (hi/lo), current tile
  short8 vh[2][4], vl[2][4];   // V^T fragments (hi/lo), current tile

  auto loadK = [&](int kt2) {
    const unsigned short *ph, *pl;
    if (kt2 < 32) { const size_t tk = (size_t)(h * 32 + kt2);
                    ph = kbkS + tk * 8192; pl = ph + 4096; }
    else          { const size_t tk = (size_t)(hkv * 16 + (kt2 - 32));
                    ph = KPhi + tk * 4096; pl = ph + 524288; }
#pragma unroll
    for (int kk = 0; kk < 2; ++kk)
#pragma unroll
      for (int nt = 0; nt < 4; ++nt) {
        kh[kk][nt] = *(const short8*)(ph + (kk * 4 + nt) * 512 + fl);
        kl[kk][nt] = *(const short8*)(pl + (kk * 4 + nt) * 512 + fl);
      }
  };
  auto loadV = [&](int kt2) {
    const unsigned short *ph, *pl;
    if (kt2 < 32) { const size_t tk = (size_t)(h * 32 + kt2);
                    ph = vtKBhi + tk * 4096; pl = ph + 4194304; }
    else          { const size_t tk = (size_t)(hkv * 16 + (kt2 - 32));
                    ph = vtPhi + tk * 4096; pl = ph + 524288; }
#pragma unroll
    for (int kk = 0; kk < 2; ++kk)
#pragma unroll
      for (int nt = 0; nt < 4; ++nt) {
        vh[kk][nt] = *(const short8*)(ph + (kk * 4 + nt) * 512 + fl);
        vl[kk][nt] = *(const short8*)(pl + (kk * 4 + nt) * 512 + fl);
      }
  };

  loadK(0);   // prologue

  for (int kt = 0; kt < ntiles; ++kt) {
    const bool isKB = kt < 32;
    loadV(kt);                          // in flight during QK+softmax
    __builtin_amdgcn_s_barrier();       // convergence only (no shared staging)

    floatx4 accs[4];
#pragma unroll
    for (int nt = 0; nt < 4; ++nt) accs[nt] = (floatx4){0.f, 0.f, 0.f, 0.f};
    if (isKB) {
#pragma unroll
      for (int kk = 0; kk < 2; ++kk)
#pragma unroll
        for (int nt = 0; nt < 4; ++nt) {
          accs[nt] = __builtin_amdgcn_mfma_f32_16x16x32_bf16(qAh[kk], kh[kk][nt], accs[nt], 0, 0, 0);
          accs[nt] = __builtin_amdgcn_mfma_f32_16x16x32_bf16(qAl[kk], kh[kk][nt], accs[nt], 0, 0, 0);
          accs[nt] = __builtin_amdgcn_mfma_f32_16x16x32_bf16(qAh[kk], kl[kk][nt], accs[nt], 0, 0, 0);
        }
    } else {
#pragma unroll
      for (int kk = 0; kk < 2; ++kk)
#pragma unroll
        for (int nt = 0; nt < 4; ++nt) {
          accs[nt] = __builtin_amdgcn_mfma_f32_16x16x32_bf16(qBh[kk], kh[kk][nt], accs[nt], 0, 0, 0);
          accs[nt] = __builtin_amdgcn_mfma_f32_16x16x32_bf16(qBl[kk], kh[kk][nt], accs[nt], 0, 0, 0);
          accs[nt] = __builtin_amdgcn_mfma_f32_16x16x32_bf16(qBh[kk], kl[kk][nt], accs[nt], 0, 0, 0);
        }
    }

    // Bias/mask: KB tiles = uniform bias; prompt non-diagonal = none; only the
    // final (diagonal) tile needs the causal mask.
    float sv[4][4];
    if (isKB) {
#pragma unroll
      for (int nt = 0; nt < 4; ++nt)
#pragma unroll
        for (int r = 0; r < 4; ++r) sv[nt][r] = accs[nt][r] + kbbias;
    } else if (kt < ntiles - 1) {
#pragma unroll
      for (int nt = 0; nt < 4; ++nt)
#pragma unroll
        for (int r = 0; r < 4; ++r) sv[nt][r] = accs[nt][r];
    } else {
#pragma unroll
      for (int nt = 0; nt < 4; ++nt) {
        int kl_ = nt * 16 + col;
#pragma unroll
        for (int r = 0; r < 4; ++r) {
          int ql_ = w * 16 + quad * 4 + r;
          sv[nt][r] = accs[nt][r] + ((kl_ <= ql_) ? 0.0f : -1e9f);
        }
      }
    }
#pragma unroll
    for (int r = 0; r < 4; ++r) {
      float rmax = fmaxf(fmaxf(sv[0][r], sv[1][r]), fmaxf(sv[2][r], sv[3][r]));
#pragma unroll
      for (int off = 8; off; off >>= 1) rmax = fmaxf(rmax, __shfl_xor(rmax, off));
      float mnew = fmaxf(m_[r], rmax);
      float alpha = __expf(m_[r] - mnew);
      float psum = 0.f;
#pragma unroll
      for (int nt = 0; nt < 4; ++nt) {
        float p = __expf(sv[nt][r] - mnew);
        sv[nt][r] = p;
        psum += p;
      }
#pragma unroll
      for (int off = 8; off; off >>= 1) psum += __shfl_xor(psum, off);
      l_[r] = l_[r] * alpha + psum;
      m_[r] = mnew;
#pragma unroll
      for (int nt = 0; nt < 4; ++nt) acco[nt][r] *= alpha;
    }

    // Prefetch next tile's K (WAR on kh/kl keeps these after the QK MFMAs;
    // in flight during P-pack + PV). Clamped redundant load on last tile.
    loadK(kt + 1 < ntiles ? kt + 1 : kt);

    // P truncation split -> packed hi|lo<<16 (err <= 2^-16 * p; p in [0,1]).
#pragma unroll
    for (int nt = 0; nt < 4; ++nt)
#pragma unroll
      for (int r = 0; r < 4; ++r) {
        unsigned xb = __float_as_uint(sv[nt][r]);
        float hf = __uint_as_float(xb & 0xffff0000u);
        unsigned db = __float_as_uint(sv[nt][r] - hf);
        Pw[(quad * 4 + r) * 68 + nt * 16 + col] = (xb >> 16) | (db & 0xffff0000u);
      }

#pragma unroll
    for (int kk = 0; kk < 2; ++kk) {
      uint4 pa = *(const uint4*)&Pw[col * 68 + kk * 32 + quad * 8];
      uint4 pb = *(const uint4*)&Pw[col * 68 + kk * 32 + quad * 8 + 4];
      union { unsigned int u[4]; short8 s; } uh, ul;
      uh.u[0] = (pa.x & 0xffffu) | (pa.y << 16);
      uh.u[1] = (pa.z & 0xffffu) | (pa.w << 16);
      uh.u[2] = (pb.x & 0xffffu) | (pb.y << 16);
      uh.u[3] = (pb.z & 0xffffu) | (pb.w << 16);
      ul.u[0] = (pa.x >> 16) | (pa.y & 0xffff0000u);
      ul.u[1] = (pa.z >> 16) | (pa.w & 0xffff0000u);
      ul.u[2] = (pb.x >> 16) | (pb.y & 0xffff0000u);
      ul.u[3] = (pb.z >> 16) | (pb.w & 0xffff0000u);
      short8 ph8 = uh.s, pl8 = ul.s;
#pragma unroll
      for (int nt = 0; nt < 4; ++nt) {
        acco[nt] = __builtin_amdgcn_mfma_f32_16x16x32_bf16(ph8, vh[kk][nt], acco[nt], 0, 0, 0);
        acco[nt] = __builtin_amdgcn_mfma_f32_16x16x32_bf16(pl8, vh[kk][nt], acco[nt], 0, 0, 0);
        acco[nt] = __builtin_amdgcn_mfma_f32_16x16x32_bf16(ph8, vl[kk][nt], acco[nt], 0, 0, 0);
      }
    }
  }

#pragma unroll
  for (int r = 0; r < 4; ++r) {
    float linv = 1.0f / l_[r];
#pragma unroll
    for (int nt = 0; nt < 4; ++nt)
      qnctx[(size_t)(q0 + w * 16 + quad * 4 + r) * 2048 + h * 64 + nt * 16 + col] =
          acco[nt][r] * linv;
  }
}

// ---------------------------------------------------------------------------
extern "C" void kernel_launch(void* const* d_in, const int* in_sizes, int n_in,
                              void* d_out, int out_size, void* d_ws, size_t ws_size,
                              hipStream_t stream) {
  (void)in_sizes; (void)n_in; (void)out_size; (void)ws_size;
  const float* hidden = (const float*)d_in[0];
  float* kbk = (float*)d_in[2];              // tile-split in place (restored each launch)
  const float* kbv = (const float*)d_in[3];
  const float* Wq  = (const float*)d_in[4];
  const float* Wk  = (const float*)d_in[5];
  const float* Wv  = (const float*)d_in[6];
  const float* Wo  = (const float*)d_in[7];
  const float* Wqn = (const float*)d_in[8];
  const int*   pos = (const int*)d_in[9];

  char* ws = (char*)d_ws;
  double* sums = (double*)(ws + WS_SUMS);
  float* dq1 = (float*)(ws + WS_DQ1);
  float* dq2 = (float*)(ws + WS_DQ2);
  unsigned short* xq   = (unsigned short*)(ws + WS_XQ);
  unsigned short* wall = (unsigned short*)(ws + WS_WALL);
  unsigned short* vtKBhi = (unsigned short*)(ws + WS_WALL);              // after GEMM
  unsigned short* vtPhi  = (unsigned short*)(ws + WS_WALL + 16777216);   // after GEMM
  unsigned short* wqo  = (unsigned short*)(ws + WS_QB);                  // after attn
  float* Qb  = (float*)(ws + WS_QB);
  unsigned short* KPhi = (unsigned short*)(ws + WS_KB);                  // prompt K hi
  unsigned short* KPlo = KPhi + 524288;                                  // prompt K lo
  float* Vb  = (float*)(ws + WS_VB);
  float* QNC = (float*)(ws + WS_QN);   // kb_q, then CTX
  float2* ropetab = (float2*)(ws + WS_ROPET);

  hipMemsetAsync(sums, 0, 64, stream);

  // RoPE table + 5-segment weight abs-sums (fused)
  k_pre<<<768, 256, 0, stream>>>(pos, ropetab, Wq, Wk, Wv, Wo, Wqn, sums);

  // Wq/Wk/Wv/Wqn ternary quant + hidden activation quant (fused)
  k_quant1<<<11264, 256, 0, stream>>>(Wq, Wk, Wv, Wqn, wall, sums, hidden, xq, dq1);

  // Fused Q/K/V/QN GEMM with RoPE epilogue: 64x64 tiles, grid 80x16 = 1280
  // blocks = exactly 5/CU.
  k_gemm64u<<<dim3(80, 16), 256, 0, stream>>>(xq, wall, dq1, sums, ropetab,
                                              Qb, KPhi, KPlo, Vb, QNC, 0);

  // V transposes (1152 blocks) + kbk in-place tile split (1024 blocks)
  k_prep<<<1152 + 1024, 256, 0, stream>>>(kbv, Vb, vtKBhi, vtPhi, kbk);

  k_attn_mfma<<<dim3(cNH, cQ / 64), 256, 0, stream>>>(
      Qb, QNC, KPhi, (const unsigned short*)kbk, vtKBhi, vtPhi);

  // Wo ternary quant + CTX activation quant (fused)
  k_quant2<<<5120, 256, 0, stream>>>(Wo, wqo, sums, QNC, xq, dq2);

  // O projection: 64x64 tiles, grid 32x16 = 512 blocks (2/CU)
  k_gemm64u<<<dim3(32, 16), 256, 0, stream>>>(xq, wqo, dq2, sums, ropetab,
                                              (float*)d_out, nullptr, nullptr,
                                              nullptr, nullptr, 1);
}